// Round 1
// baseline (995.383 us; speedup 1.0000x reference)
//
#include <hip/hip_runtime.h>
#include <cstddef>

// InvariantPointAttention + surface cross-attention, B=1, N=512, M=2048,
// H=12, C_H=16, C_S=384, C_Z=128, PQ=4, PV=8. All f32.
//
// Kernel plan (round 0 baseline, correctness-first):
//  k_proj_s    : q/k/v/sq + rotated qp/kp/vp from s           (128 blocks)
//  k_proj_surf : surface_feat, sk, sv                          (256 blocks)
//  k_zpass     : z -> [sqrt(1/3)*b_bias | pair_z] fused, z read once (512)
//  k_attn      : per-i IPA: logits+softmax+o/o_pt/o_pair -> o_cat (512)
//  k_surf      : per-(h,n-tile) surface attn, online softmax -> o_cat (384)
//  k_ts        : per-m-tile transposed softmax + s_agg          (256)
//  k_surf_out  : [surface_feat|s_agg] @ Wso -> d_out tail       (128)
//  k_out       : o_cat @ Wout -> d_out head                     (128)

#define CS 384
#define INFV 100000.0f

__device__ __forceinline__ float softplusf(float x) { return log1pf(__expf(x)); }

// ---------------------------------------------------------------- K1
__global__ __launch_bounds__(256) void k_proj_s(
    const float* __restrict__ s, const float* __restrict__ rots, const float* __restrict__ trans,
    const float* __restrict__ Wq, const float* __restrict__ bq,
    const float* __restrict__ Wkv, const float* __restrict__ bkv,
    const float* __restrict__ Wqp, const float* __restrict__ bqp,
    const float* __restrict__ Wkvp, const float* __restrict__ bkvp,
    const float* __restrict__ Wsq, const float* __restrict__ bsq,
    float* __restrict__ qw, float* __restrict__ kw, float* __restrict__ vw,
    float* __restrict__ sqw, float* __restrict__ qpw, float* __restrict__ kpw,
    float* __restrict__ vpw)
{
    __shared__ float srow[4][CS];
    __shared__ float plin[4][576];  // qp_lin(144) | kvp_lin(432)
    const int n0 = blockIdx.x * 4;
    const int t = threadIdx.x;
    for (int idx = t; idx < 384; idx += 256) {
        int r = idx / 96, c4 = (idx % 96) * 4;
        *(float4*)&srow[r][c4] = *(const float4*)&s[(size_t)(n0 + r) * CS + c4];
    }
    __syncthreads();

    // q (192)
    for (int c = t; c < 192; c += 256) {
        float b = bq[c]; float a0 = b, a1 = b, a2 = b, a3 = b;
        #pragma unroll 4
        for (int kk = 0; kk < CS; ++kk) {
            float w = Wq[kk * 192 + c];
            a0 = fmaf(srow[0][kk], w, a0); a1 = fmaf(srow[1][kk], w, a1);
            a2 = fmaf(srow[2][kk], w, a2); a3 = fmaf(srow[3][kk], w, a3);
        }
        qw[(size_t)(n0+0)*192+c]=a0; qw[(size_t)(n0+1)*192+c]=a1;
        qw[(size_t)(n0+2)*192+c]=a2; qw[(size_t)(n0+3)*192+c]=a3;
    }
    // sq (192)
    for (int c = t; c < 192; c += 256) {
        float b = bsq[c]; float a0 = b, a1 = b, a2 = b, a3 = b;
        #pragma unroll 4
        for (int kk = 0; kk < CS; ++kk) {
            float w = Wsq[kk * 192 + c];
            a0 = fmaf(srow[0][kk], w, a0); a1 = fmaf(srow[1][kk], w, a1);
            a2 = fmaf(srow[2][kk], w, a2); a3 = fmaf(srow[3][kk], w, a3);
        }
        sqw[(size_t)(n0+0)*192+c]=a0; sqw[(size_t)(n0+1)*192+c]=a1;
        sqw[(size_t)(n0+2)*192+c]=a2; sqw[(size_t)(n0+3)*192+c]=a3;
    }
    // kv (384) -> k,v  (row reshape (12,32): first 16 = k, last 16 = v)
    for (int c = t; c < 384; c += 256) {
        float b = bkv[c]; float a0 = b, a1 = b, a2 = b, a3 = b;
        #pragma unroll 4
        for (int kk = 0; kk < CS; ++kk) {
            float w = Wkv[kk * 384 + c];
            a0 = fmaf(srow[0][kk], w, a0); a1 = fmaf(srow[1][kk], w, a1);
            a2 = fmaf(srow[2][kk], w, a2); a3 = fmaf(srow[3][kk], w, a3);
        }
        int h = c >> 5, cc = c & 31;
        float* dst = (cc < 16) ? kw : vw;
        int col = h * 16 + (cc & 15);
        dst[(size_t)(n0+0)*192+col]=a0; dst[(size_t)(n0+1)*192+col]=a1;
        dst[(size_t)(n0+2)*192+col]=a2; dst[(size_t)(n0+3)*192+col]=a3;
    }
    // qp_lin (144)
    for (int c = t; c < 144; c += 256) {
        float b = bqp[c]; float a0 = b, a1 = b, a2 = b, a3 = b;
        #pragma unroll 4
        for (int kk = 0; kk < CS; ++kk) {
            float w = Wqp[kk * 144 + c];
            a0 = fmaf(srow[0][kk], w, a0); a1 = fmaf(srow[1][kk], w, a1);
            a2 = fmaf(srow[2][kk], w, a2); a3 = fmaf(srow[3][kk], w, a3);
        }
        plin[0][c]=a0; plin[1][c]=a1; plin[2][c]=a2; plin[3][c]=a3;
    }
    // kvp_lin (432)
    for (int c = t; c < 432; c += 256) {
        float b = bkvp[c]; float a0 = b, a1 = b, a2 = b, a3 = b;
        #pragma unroll 4
        for (int kk = 0; kk < CS; ++kk) {
            float w = Wkvp[kk * 432 + c];
            a0 = fmaf(srow[0][kk], w, a0); a1 = fmaf(srow[1][kk], w, a1);
            a2 = fmaf(srow[2][kk], w, a2); a3 = fmaf(srow[3][kk], w, a3);
        }
        plin[0][144+c]=a0; plin[1][144+c]=a1; plin[2][144+c]=a2; plin[3][144+c]=a3;
    }
    __syncthreads();
    // rigid transform: out[p][d] = sum_j R[d][j]*lin[j*stride+p] + tr[d]
    for (int idx = t; idx < 2304; idx += 256) {
        int r = idx / 576, rem = idx % 576;
        int n = n0 + r;
        const float* R = &rots[(size_t)n * 9];
        const float* tr = &trans[(size_t)n * 3];
        if (rem < 144) {
            int p = rem / 3, d = rem % 3;
            float v = fmaf(R[d*3+0], plin[r][p],
                      fmaf(R[d*3+1], plin[r][48+p],
                      fmaf(R[d*3+2], plin[r][96+p], tr[d])));
            qpw[(size_t)n * 144 + p * 3 + d] = v;  // p = h*4+pq
        } else {
            int rem2 = rem - 144; int p = rem2 / 3, d = rem2 % 3;
            float v = fmaf(R[d*3+0], plin[r][144+p],
                      fmaf(R[d*3+1], plin[r][288+p],
                      fmaf(R[d*3+2], plin[r][432+p], tr[d])));
            int h = p / 12, ii = p % 12;  // p = h*12+ii; ii<4 -> kp else vp
            if (ii < 4) kpw[(size_t)n * 144 + h * 12 + ii * 3 + d] = v;
            else        vpw[(size_t)n * 288 + h * 24 + (ii - 4) * 3 + d] = v;
        }
    }
}

// ---------------------------------------------------------------- K2
__global__ __launch_bounds__(256) void k_proj_surf(
    const float* __restrict__ sf, const float* __restrict__ Wse, const float* __restrict__ bse,
    const float* __restrict__ Wsk, const float* __restrict__ bsk,
    const float* __restrict__ Wsv, const float* __restrict__ bsv,
    float* __restrict__ sfeat, float* __restrict__ skw, float* __restrict__ svw)
{
    __shared__ float feat[8][CS];
    const int m0 = blockIdx.x * 8, t = threadIdx.x;
    for (int idx = t; idx < 8 * CS; idx += 256) {
        int r = idx / CS, c = idx % CS;
        const float* row = &sf[(size_t)(m0 + r) * 16];
        float a = bse[c];
        #pragma unroll
        for (int kk = 0; kk < 16; ++kk) a = fmaf(row[kk], Wse[kk * CS + c], a);
        feat[r][c] = a;
        sfeat[(size_t)(m0 + r) * CS + c] = a;
    }
    __syncthreads();
    for (int c = t; c < 384; c += 256) {
        const bool isk = c < 192;
        const int cc = isk ? c : c - 192;
        const float* W = isk ? Wsk : Wsv;
        float b = isk ? bsk[cc] : bsv[cc];
        float a[8];
        #pragma unroll
        for (int r = 0; r < 8; ++r) a[r] = b;
        #pragma unroll 2
        for (int kk = 0; kk < CS; ++kk) {
            float w = W[kk * 192 + cc];
            #pragma unroll
            for (int r = 0; r < 8; ++r) a[r] = fmaf(feat[r][kk], w, a[r]);
        }
        float* dst = isk ? skw : svw;
        #pragma unroll
        for (int r = 0; r < 8; ++r) dst[(size_t)(m0 + r) * 192 + cc] = a[r];
    }
}

// ---------------------------------------------------------------- K3
// bpz[i][c][j]: c<12 -> sqrt(1/3)*(z@Wb+bb)[h=c], c>=12 -> (z@Wdz+bdz)[c-12]
__global__ __launch_bounds__(256) void k_zpass(
    const float* __restrict__ z, const float* __restrict__ Wb, const float* __restrict__ bb,
    const float* __restrict__ Wdz, const float* __restrict__ bdz, float* __restrict__ bpz)
{
    __shared__ float Wt[44][128];
    __shared__ float bias_s[44];
    __shared__ float zt[64][132];  // pad 132: stride%32=4 -> conflict-light
    const int i = blockIdx.x, t = threadIdx.x;
    const float s3 = 0.5773502691896258f;
    for (int idx = t; idx < 44 * 128; idx += 256) {
        int c = idx >> 7, kk = idx & 127;
        Wt[c][kk] = (c < 12) ? s3 * Wb[kk * 12 + c] : Wdz[kk * 32 + (c - 12)];
    }
    if (t < 44) bias_s[t] = (t < 12) ? s3 * bb[t] : bdz[t - 12];
    const int jl = t & 63, cg = t >> 6;  // cg uniform per wave
    for (int j0 = 0; j0 < 512; j0 += 64) {
        __syncthreads();
        for (int idx = t; idx < 2048; idx += 256) {
            int r = idx >> 5, c4 = (idx & 31) << 2;
            *(float4*)&zt[r][c4] = *(const float4*)&z[((size_t)i * 512 + j0 + r) * 128 + c4];
        }
        __syncthreads();
        float acc[11];
        #pragma unroll
        for (int u = 0; u < 11; ++u) acc[u] = bias_s[cg * 11 + u];
        #pragma unroll 2
        for (int k4 = 0; k4 < 128; k4 += 4) {
            float4 zv = *(float4*)&zt[jl][k4];
            #pragma unroll
            for (int u = 0; u < 11; ++u) {
                float4 wv = *(float4*)&Wt[cg * 11 + u][k4];
                acc[u] = fmaf(zv.x, wv.x, acc[u]);
                acc[u] = fmaf(zv.y, wv.y, acc[u]);
                acc[u] = fmaf(zv.z, wv.z, acc[u]);
                acc[u] = fmaf(zv.w, wv.w, acc[u]);
            }
        }
        #pragma unroll
        for (int u = 0; u < 11; ++u)
            bpz[((size_t)i * 44 + cg * 11 + u) * 512 + j0 + jl] = acc[u];
    }
}

// ---------------------------------------------------------------- K4
__global__ __launch_bounds__(256) void k_attn(
    const float* __restrict__ qw, const float* __restrict__ kw, const float* __restrict__ vw,
    const float* __restrict__ qpw, const float* __restrict__ kpw, const float* __restrict__ vpw,
    const float* __restrict__ bpz, const float* __restrict__ mask,
    const float* __restrict__ rots, const float* __restrict__ trans,
    const float* __restrict__ hwp, float* __restrict__ ocat)
{
    __shared__ float pls[12 * 516];  // stride 516: bank = (h*4+j)%32
    __shared__ float qs[192], qps[144], opt[288], cpt[12], red[4];
    const int i = blockIdx.x, t = threadIdx.x;
    if (t < 192) qs[t] = qw[(size_t)i * 192 + t];
    if (t < 144) qps[t] = qpw[(size_t)i * 144 + t];
    if (t < 12) cpt[t] = -0.5f * 0.13608276348795434f * softplusf(hwp[t]);
    const float mask_i = mask[i];
    __syncthreads();
    // phase 1: logits
    for (int hj = t; hj < 6144; hj += 256) {
        int h = hj >> 9, j = hj & 511;
        float kj[16], kpj[12];
        { const float4* kr = (const float4*)&kw[(size_t)j * 192 + h * 16];
          *(float4*)&kj[0] = kr[0]; *(float4*)&kj[4] = kr[1];
          *(float4*)&kj[8] = kr[2]; *(float4*)&kj[12] = kr[3]; }
        { const float4* kr = (const float4*)&kpw[(size_t)j * 144 + h * 12];
          *(float4*)&kpj[0] = kr[0]; *(float4*)&kpj[4] = kr[1]; *(float4*)&kpj[8] = kr[2]; }
        float qk = 0.f;
        #pragma unroll
        for (int c = 0; c < 16; ++c) qk = fmaf(qs[h * 16 + c], kj[c], qk);
        float pts = 0.f;
        #pragma unroll
        for (int p = 0; p < 4; ++p) {
            float dx = qps[h*12+p*3+0] - kpj[p*3+0];
            float dy = qps[h*12+p*3+1] - kpj[p*3+1];
            float dz = qps[h*12+p*3+2] - kpj[p*3+2];
            pts += dx*dx + dy*dy + dz*dz;
        }
        float lg = fmaf(0.14433756729740643f, qk, bpz[((size_t)i * 44 + h) * 512 + j]);
        lg = fmaf(cpt[h], pts, lg);
        lg += INFV * (mask_i * mask[j] - 1.0f);
        pls[h * 516 + j] = lg;
    }
    __syncthreads();
    // phase 2: softmax per head over j
    for (int h = 0; h < 12; ++h) {
        float v0 = pls[h * 516 + t], v1 = pls[h * 516 + 256 + t];
        float mx = fmaxf(v0, v1);
        #pragma unroll
        for (int off = 32; off; off >>= 1) mx = fmaxf(mx, __shfl_xor(mx, off));
        if ((t & 63) == 0) red[t >> 6] = mx;
        __syncthreads();
        mx = fmaxf(fmaxf(red[0], red[1]), fmaxf(red[2], red[3]));
        __syncthreads();
        float e0 = __expf(v0 - mx), e1 = __expf(v1 - mx);
        float sm = e0 + e1;
        #pragma unroll
        for (int off = 32; off; off >>= 1) sm += __shfl_xor(sm, off);
        if ((t & 63) == 0) red[t >> 6] = sm;
        __syncthreads();
        float inv = 1.0f / (red[0] + red[1] + red[2] + red[3]);
        pls[h * 516 + t] = e0 * inv;
        pls[h * 516 + 256 + t] = e1 * inv;
        __syncthreads();
    }
    // phase 3: o (192) and o_pt global-frame (288)
    for (int rnd = 0; rnd < 2; ++rnd) {
        int oi = t + rnd * 256;
        if (oi < 480) {
            int h, stride; const float* src;
            if (oi < 192) { h = oi >> 4; src = vw + oi; stride = 192; }
            else { h = (oi - 192) / 24; src = vpw + (oi - 192); stride = 288; }
            const float* pr = &pls[h * 516];
            float a0 = 0, a1 = 0, a2 = 0, a3 = 0;
            for (int j = 0; j < 512; j += 4) {
                a0 = fmaf(pr[j+0], src[(size_t)(j+0) * stride], a0);
                a1 = fmaf(pr[j+1], src[(size_t)(j+1) * stride], a1);
                a2 = fmaf(pr[j+2], src[(size_t)(j+2) * stride], a2);
                a3 = fmaf(pr[j+3], src[(size_t)(j+3) * stride], a3);
            }
            float acc = (a0 + a1) + (a2 + a3);
            if (oi < 192) ocat[(size_t)i * 1152 + oi] = acc;
            else opt[oi - 192] = acc;
        }
    }
    // phase 4: o_pair[h][c] = sum_j p[h][j]*pz[c][j]  (wave per output)
    {
        int w = t >> 6, lane = t & 63;
        for (int u = 0; u < 96; ++u) {
            int oi = w * 96 + u; int h = oi >> 5, c = oi & 31;
            const float* pz = &bpz[((size_t)i * 44 + 12 + c) * 512];
            const float* pr = &pls[h * 516];
            float sacc = 0.f;
            #pragma unroll
            for (int jj = 0; jj < 8; ++jj)
                sacc = fmaf(pr[lane + jj * 64], pz[lane + jj * 64], sacc);
            #pragma unroll
            for (int off = 32; off; off >>= 1) sacc += __shfl_xor(sacc, off);
            if (lane == 0) ocat[(size_t)i * 1152 + 576 + oi] = sacc;
        }
    }
    __syncthreads();
    // phase 5: finalize o_pt: local = R^T (opt - trans), norm
    if (t < 96) {
        int h = t >> 3, p = t & 7;
        const float* R = &rots[(size_t)i * 9];
        float gx = opt[h*24 + p*3 + 0] - trans[(size_t)i*3 + 0];
        float gy = opt[h*24 + p*3 + 1] - trans[(size_t)i*3 + 1];
        float gz = opt[h*24 + p*3 + 2] - trans[(size_t)i*3 + 2];
        float lx = R[0]*gx + R[3]*gy + R[6]*gz;
        float ly = R[1]*gx + R[4]*gy + R[7]*gz;
        float lz = R[2]*gx + R[5]*gy + R[8]*gz;
        float nm = sqrtf(lx*lx + ly*ly + lz*lz + 1e-8f);
        int col = h * 8 + p;
        size_t base = (size_t)i * 1152;
        ocat[base + 192 + col] = lx;
        ocat[base + 288 + col] = ly;
        ocat[base + 384 + col] = lz;
        ocat[base + 480 + col] = nm;
    }
}

// ---------------------------------------------------------------- K5 (o_surf)
__global__ __launch_bounds__(256) void k_surf(
    const float* __restrict__ sqw, const float* __restrict__ skw, const float* __restrict__ svw,
    const float* __restrict__ trans, const float* __restrict__ mask,
    const float* __restrict__ sp, const float* __restrict__ smask,
    const float* __restrict__ sbwp, float* __restrict__ ocat)
{
    __shared__ float sk_t[256][17];
    __shared__ float sv_t[256][17];
    __shared__ float sp_t[768];
    __shared__ float smask_t[256];
    const int h = blockIdx.x >> 5;
    const int n0 = (blockIdx.x & 31) * 16;
    const int t = threadIdx.x;
    const int tn = t >> 4, tm = t & 15;
    const int n = n0 + tn;
    const float sbw = softplusf(sbwp[0]);
    float qreg[16];
    #pragma unroll
    for (int c = 0; c < 16; ++c) qreg[c] = sqw[(size_t)n * 192 + h * 16 + c];
    const float trx = trans[(size_t)n*3+0], tryy = trans[(size_t)n*3+1], trz = trans[(size_t)n*3+2];
    const float mask_n = mask[n];
    float mx = -1e30f, l = 0.f;
    // pass 1: online max/sum over m
    for (int tile = 0; tile < 8; ++tile) {
        __syncthreads();
        const int mb = tile * 256;
        for (int idx = t; idx < 1024; idx += 256) {
            int ml = idx >> 2, c4 = (idx & 3) << 2;
            float4 v4 = *(const float4*)&skw[(size_t)(mb + ml) * 192 + h * 16 + c4];
            sk_t[ml][c4+0]=v4.x; sk_t[ml][c4+1]=v4.y; sk_t[ml][c4+2]=v4.z; sk_t[ml][c4+3]=v4.w;
        }
        for (int idx = t; idx < 768; idx += 256) sp_t[idx] = sp[(size_t)mb * 3 + idx];
        smask_t[t] = smask[mb + t];
        __syncthreads();
        for (int kk = 0; kk < 16; ++kk) {
            int ml = tm + (kk << 4);
            float dot = 0.f;
            #pragma unroll
            for (int c = 0; c < 16; ++c) dot = fmaf(qreg[c], sk_t[ml][c], dot);
            float dx = trx - sp_t[ml*3+0], dy = tryy - sp_t[ml*3+1], dz = trz - sp_t[ml*3+2];
            float lg = fmaf(0.25f, dot, -0.5f * sbw * (dx*dx + dy*dy + dz*dz));
            lg += INFV * (mask_n * smask_t[ml] - 1.0f);
            float mn = fmaxf(mx, lg);
            l = l * __expf(mx - mn) + __expf(lg - mn);
            mx = mn;
        }
    }
    #pragma unroll
    for (int off = 1; off < 16; off <<= 1) {
        float m2 = __shfl_xor(mx, off), l2 = __shfl_xor(l, off);
        float mn = fmaxf(mx, m2);
        l = l * __expf(mx - mn) + l2 * __expf(m2 - mn);
        mx = mn;
    }
    const float invl = 1.0f / l;
    float acc[16];
    #pragma unroll
    for (int c = 0; c < 16; ++c) acc[c] = 0.f;
    // pass 2: weighted sum of sv
    for (int tile = 0; tile < 8; ++tile) {
        __syncthreads();
        const int mb = tile * 256;
        for (int idx = t; idx < 1024; idx += 256) {
            int ml = idx >> 2, c4 = (idx & 3) << 2;
            float4 v4 = *(const float4*)&skw[(size_t)(mb + ml) * 192 + h * 16 + c4];
            sk_t[ml][c4+0]=v4.x; sk_t[ml][c4+1]=v4.y; sk_t[ml][c4+2]=v4.z; sk_t[ml][c4+3]=v4.w;
            float4 w4 = *(const float4*)&svw[(size_t)(mb + ml) * 192 + h * 16 + c4];
            sv_t[ml][c4+0]=w4.x; sv_t[ml][c4+1]=w4.y; sv_t[ml][c4+2]=w4.z; sv_t[ml][c4+3]=w4.w;
        }
        for (int idx = t; idx < 768; idx += 256) sp_t[idx] = sp[(size_t)mb * 3 + idx];
        smask_t[t] = smask[mb + t];
        __syncthreads();
        for (int kk = 0; kk < 16; ++kk) {
            int ml = tm + (kk << 4);
            float dot = 0.f;
            #pragma unroll
            for (int c = 0; c < 16; ++c) dot = fmaf(qreg[c], sk_t[ml][c], dot);
            float dx = trx - sp_t[ml*3+0], dy = tryy - sp_t[ml*3+1], dz = trz - sp_t[ml*3+2];
            float lg = fmaf(0.25f, dot, -0.5f * sbw * (dx*dx + dy*dy + dz*dz));
            lg += INFV * (mask_n * smask_t[ml] - 1.0f);
            float w = __expf(lg - mx) * invl;
            #pragma unroll
            for (int c = 0; c < 16; ++c) acc[c] = fmaf(w, sv_t[ml][c], acc[c]);
        }
    }
    #pragma unroll
    for (int off = 1; off < 16; off <<= 1) {
        #pragma unroll
        for (int c = 0; c < 16; ++c) acc[c] += __shfl_xor(acc[c], off);
    }
    float outv = 0.f;
    #pragma unroll
    for (int c = 0; c < 16; ++c) if (tm == c) outv = acc[c];  // static idx
    ocat[(size_t)n * 1152 + 960 + h * 16 + tm] = outv;
}

// ---------------------------------------------------------------- K6 (a_ts+s_agg)
__global__ __launch_bounds__(256) void k_ts(
    const float* __restrict__ s, const float* __restrict__ sqw, const float* __restrict__ skw,
    const float* __restrict__ trans, const float* __restrict__ mask,
    const float* __restrict__ sp, const float* __restrict__ smask,
    const float* __restrict__ sbwp, float* __restrict__ saggw)
{
    __shared__ float big[32 * 384];  // sqt (stride 196) / s tile (stride 384)
    __shared__ float sk_l[1536];
    __shared__ float w_lds[8][32];
    __shared__ float spm[24], smaskm[8];
    __shared__ float trans_t[96], mask_t[32];
    const int m0 = blockIdx.x * 8, t = threadIdx.x;
    const int tm = t >> 5, tn = t & 31;
    const float sbw = softplusf(sbwp[0]);
    for (int idx = t; idx < 1536; idx += 256) sk_l[idx] = skw[(size_t)m0 * 192 + idx];
    if (t < 24) spm[t] = sp[(size_t)m0 * 3 + t];
    if (t < 8) smaskm[t] = smask[m0 + t];
    __syncthreads();
    const float spx = spm[tm*3+0], spy = spm[tm*3+1], spz = spm[tm*3+2];
    const float smk = smaskm[tm];
    float mxr[12], lr[12];
    #pragma unroll
    for (int h = 0; h < 12; ++h) { mxr[h] = -1e30f; lr[h] = 0.f; }
    // pass 1: per-(h, m=m0+tm) online max/sum over n (tn-strided)
    for (int tile = 0; tile < 16; ++tile) {
        __syncthreads();
        const int nb = tile * 32;
        for (int idx = t; idx < 1536; idx += 256) {
            int nn = idx / 48, c4 = (idx % 48) * 4;
            *(float4*)&big[nn * 196 + c4] = *(const float4*)&sqw[(size_t)(nb + nn) * 192 + c4];
        }
        if (t < 96) trans_t[t] = trans[(size_t)nb * 3 + t];
        if (t < 32) mask_t[t] = mask[nb + t];
        __syncthreads();
        float dx = spx - trans_t[tn*3+0], dy = spy - trans_t[tn*3+1], dz = spz - trans_t[tn*3+2];
        float mterm = INFV * (mask_t[tn] * smk - 1.0f) - 0.5f * sbw * (dx*dx + dy*dy + dz*dz);
        #pragma unroll
        for (int h = 0; h < 12; ++h) {
            float dot = 0.f;
            #pragma unroll
            for (int c = 0; c < 16; ++c)
                dot = fmaf(big[tn * 196 + h * 16 + c], sk_l[tm * 192 + h * 16 + c], dot);
            float lg = fmaf(0.25f, dot, mterm);
            float mn = fmaxf(mxr[h], lg);
            lr[h] = lr[h] * __expf(mxr[h] - mn) + __expf(lg - mn);
            mxr[h] = mn;
        }
    }
    #pragma unroll
    for (int h = 0; h < 12; ++h) {
        float mx = mxr[h], l = lr[h];
        #pragma unroll
        for (int off = 1; off < 32; off <<= 1) {
            float m2 = __shfl_xor(mx, off), l2 = __shfl_xor(l, off);
            float mn = fmaxf(mx, m2);
            l = l * __expf(mx - mn) + l2 * __expf(m2 - mn);
            mx = mn;
        }
        mxr[h] = mx; lr[h] = 1.0f / l;
    }
    // pass 2: w = mean_h softmax_h; s_agg[m] += w * s[n]
    float acc[12];
    #pragma unroll
    for (int u = 0; u < 12; ++u) acc[u] = 0.f;
    for (int tile = 0; tile < 16; ++tile) {
        __syncthreads();
        const int nb = tile * 32;
        for (int idx = t; idx < 1536; idx += 256) {
            int nn = idx / 48, c4 = (idx % 48) * 4;
            *(float4*)&big[nn * 196 + c4] = *(const float4*)&sqw[(size_t)(nb + nn) * 192 + c4];
        }
        if (t < 96) trans_t[t] = trans[(size_t)nb * 3 + t];
        if (t < 32) mask_t[t] = mask[nb + t];
        __syncthreads();
        {
            float dx = spx - trans_t[tn*3+0], dy = spy - trans_t[tn*3+1], dz = spz - trans_t[tn*3+2];
            float mterm = INFV * (mask_t[tn] * smk - 1.0f) - 0.5f * sbw * (dx*dx + dy*dy + dz*dz);
            float w = 0.f;
            #pragma unroll
            for (int h = 0; h < 12; ++h) {
                float dot = 0.f;
                #pragma unroll
                for (int c = 0; c < 16; ++c)
                    dot = fmaf(big[tn * 196 + h * 16 + c], sk_l[tm * 192 + h * 16 + c], dot);
                float lg = fmaf(0.25f, dot, mterm);
                w += __expf(lg - mxr[h]) * lr[h];
            }
            w_lds[tm][tn] = w * (1.0f / 12.0f);
        }
        __syncthreads();
        for (int idx = t; idx < 3072; idx += 256) {
            int nn = idx / 96, c4 = (idx % 96) * 4;
            *(float4*)&big[nn * 384 + c4] = *(const float4*)&s[(size_t)(nb + nn) * 384 + c4];
        }
        __syncthreads();
        for (int nn = 0; nn < 32; ++nn) {
            float wv = w_lds[tm][nn];
            #pragma unroll
            for (int u = 0; u < 12; ++u)
                acc[u] = fmaf(wv, big[nn * 384 + tn * 12 + u], acc[u]);
        }
    }
    #pragma unroll
    for (int u = 0; u < 12; ++u)
        saggw[(size_t)(m0 + tm) * 384 + tn * 12 + u] = acc[u];
}

// ---------------------------------------------------------------- K7
__global__ __launch_bounds__(256) void k_surf_out(
    const float* __restrict__ sfeat, const float* __restrict__ saggw,
    const float* __restrict__ Wso, const float* __restrict__ bso, float* __restrict__ out)
{
    const int t = threadIdx.x;
    const int m = blockIdx.x * 16 + (t >> 4);
    const int c = t & 15;
    const float* fr = &sfeat[(size_t)m * 384];
    const float* ar = &saggw[(size_t)m * 384];
    float o = bso[c];
    #pragma unroll 4
    for (int kk = 0; kk < 384; ++kk) o = fmaf(fr[kk], Wso[kk * 16 + c], o);
    #pragma unroll 4
    for (int kk = 0; kk < 384; ++kk) o = fmaf(ar[kk], Wso[(384 + kk) * 16 + c], o);
    out[196608 + (size_t)m * 16 + c] = o;
}

// ---------------------------------------------------------------- K8
__global__ __launch_bounds__(256) void k_out(
    const float* __restrict__ ocat, const float* __restrict__ Wout,
    const float* __restrict__ bout, float* __restrict__ out)
{
    __shared__ float rowl[4 * 1152];
    const int n0 = blockIdx.x * 4, t = threadIdx.x;
    for (int idx = t; idx < 1152; idx += 256)
        *(float4*)&rowl[idx * 4] = *(const float4*)&ocat[(size_t)n0 * 1152 + idx * 4];
    __syncthreads();
    for (int c = t; c < 384; c += 256) {
        float b = bout[c]; float a0 = b, a1 = b, a2 = b, a3 = b;
        #pragma unroll 4
        for (int kk = 0; kk < 1152; ++kk) {
            float w = Wout[kk * 384 + c];
            a0 = fmaf(rowl[kk], w, a0);
            a1 = fmaf(rowl[1152 + kk], w, a1);
            a2 = fmaf(rowl[2304 + kk], w, a2);
            a3 = fmaf(rowl[3456 + kk], w, a3);
        }
        out[(size_t)(n0+0)*384+c]=a0; out[(size_t)(n0+1)*384+c]=a1;
        out[(size_t)(n0+2)*384+c]=a2; out[(size_t)(n0+3)*384+c]=a3;
    }
}

// ----------------------------------------------------------------
extern "C" void kernel_launch(void* const* d_in, const int* in_sizes, int n_in,
                              void* d_out, int out_size, void* d_ws, size_t ws_size,
                              hipStream_t stream)
{
    (void)in_sizes; (void)n_in; (void)out_size; (void)ws_size;
    const float* s     = (const float*)d_in[0];
    const float* z     = (const float*)d_in[1];
    const float* rots  = (const float*)d_in[2];
    const float* trans = (const float*)d_in[3];
    const float* mask  = (const float*)d_in[4];
    const float* sp    = (const float*)d_in[5];
    const float* sf    = (const float*)d_in[6];
    const float* smask = (const float*)d_in[7];
    const float* Wq    = (const float*)d_in[8];  const float* bq   = (const float*)d_in[9];
    const float* Wkv   = (const float*)d_in[10]; const float* bkv  = (const float*)d_in[11];
    const float* Wqp   = (const float*)d_in[12]; const float* bqp  = (const float*)d_in[13];
    const float* Wkvp  = (const float*)d_in[14]; const float* bkvp = (const float*)d_in[15];
    const float* Wse   = (const float*)d_in[16]; const float* bse  = (const float*)d_in[17];
    const float* Wsq   = (const float*)d_in[18]; const float* bsq  = (const float*)d_in[19];
    const float* Wsk   = (const float*)d_in[20]; const float* bsk  = (const float*)d_in[21];
    const float* Wsv   = (const float*)d_in[22]; const float* bsv  = (const float*)d_in[23];
    const float* Wb    = (const float*)d_in[24]; const float* bb   = (const float*)d_in[25];
    const float* Wdz   = (const float*)d_in[26]; const float* bdz  = (const float*)d_in[27];
    const float* hw    = (const float*)d_in[28]; const float* sbw  = (const float*)d_in[29];
    const float* Wout  = (const float*)d_in[30]; const float* bout = (const float*)d_in[31];
    const float* Wso   = (const float*)d_in[32]; const float* bso  = (const float*)d_in[33];
    float* out = (float*)d_out;

    float* qw    = (float*)d_ws;
    float* kw    = qw    + (size_t)512 * 192;
    float* vw    = kw    + (size_t)512 * 192;
    float* sqw   = vw    + (size_t)512 * 192;
    float* qpw   = sqw   + (size_t)512 * 192;
    float* kpw   = qpw   + (size_t)512 * 144;
    float* vpw   = kpw   + (size_t)512 * 144;
    float* sfeat = vpw   + (size_t)512 * 288;
    float* skw   = sfeat + (size_t)2048 * 384;
    float* svw   = skw   + (size_t)2048 * 192;
    float* ocat  = svw   + (size_t)2048 * 192;
    float* sagg  = ocat  + (size_t)512 * 1152;
    float* bpz   = sagg  + (size_t)2048 * 384;   // 512*44*512 floats

    k_proj_s<<<dim3(128), dim3(256), 0, stream>>>(s, rots, trans, Wq, bq, Wkv, bkv,
        Wqp, bqp, Wkvp, bkvp, Wsq, bsq, qw, kw, vw, sqw, qpw, kpw, vpw);
    k_proj_surf<<<dim3(256), dim3(256), 0, stream>>>(sf, Wse, bse, Wsk, bsk, Wsv, bsv,
        sfeat, skw, svw);
    k_zpass<<<dim3(512), dim3(256), 0, stream>>>(z, Wb, bb, Wdz, bdz, bpz);
    k_attn<<<dim3(512), dim3(256), 0, stream>>>(qw, kw, vw, qpw, kpw, vpw, bpz, mask,
        rots, trans, hw, ocat);
    k_surf<<<dim3(384), dim3(256), 0, stream>>>(sqw, skw, svw, trans, mask, sp, smask,
        sbw, ocat);
    k_ts<<<dim3(256), dim3(256), 0, stream>>>(s, sqw, skw, trans, mask, sp, smask,
        sbw, sagg);
    k_surf_out<<<dim3(128), dim3(256), 0, stream>>>(sfeat, sagg, Wso, bso, out);
    k_out<<<dim3(128), dim3(256), 0, stream>>>(ocat, Wout, bout, out);
}

// Round 2
// 621.583 us; speedup vs baseline: 1.6014x; 1.6014x over previous
//
#include <hip/hip_runtime.h>
#include <cstddef>

// IPA + surface cross-attention, B=1, N=512, M=2048, H=12, C_H=16, C_S=384.
// Round 1: replace latency-bound scalar-W projection kernels with a packed
// transposed-weight tiled f32 GEMM (64x64 tile, LDS-staged, conflict-free).
//  k_pack      : transpose/concat all W into Wt[N][K] + packed biases
//  k_gemm<K>   : C[M,N] = A[M,K] @ Wt[N,K]^T + b   (proj_s / surf_kv / out)
//  k_scatter   : proj -> q/k/v/sq + rigid qp/kp/vp
//  k_sfeat     : surface_features @ Wse (K=16)
//  k_zpass     : z -> [sqrt(1/3)*b_bias | pair_z], z read once
//  k_attn      : per-i IPA attention -> o_cat            (unchanged)
//  k_surf      : flash surface attention -> o_cat        (skv layout)
//  k_ts        : transposed softmax + s_agg              (skv layout)
//  k_surf_out  : [sfeat|s_agg] @ Wso -> d_out tail (LDS-staged Wso)

#define CS 384
#define INFV 100000.0f

__device__ __forceinline__ float softplusf(float x) { return log1pf(__expf(x)); }

// ---------------------------------------------------------------- pack
// wt1[1344][384]: cols [Wq|Wsq|Wkv|Wqp|Wkvp]; wt2[384][384]: [Wsk|Wsv];
// wt3[384][1152]: Wout^T. b1[1344], b2[384].
__global__ __launch_bounds__(256) void k_pack(
    const float* __restrict__ Wq, const float* __restrict__ Wsq,
    const float* __restrict__ Wkv, const float* __restrict__ Wqp,
    const float* __restrict__ Wkvp, const float* __restrict__ Wsk,
    const float* __restrict__ Wsv, const float* __restrict__ Wout,
    const float* __restrict__ bq, const float* __restrict__ bsq,
    const float* __restrict__ bkv, const float* __restrict__ bqp,
    const float* __restrict__ bkvp, const float* __restrict__ bsk,
    const float* __restrict__ bsv,
    float* __restrict__ wt1, float* __restrict__ wt2, float* __restrict__ wt3,
    float* __restrict__ b1, float* __restrict__ b2)
{
    const int b = blockIdx.x, t = threadIdx.x;
    if (b >= 1092) {  // bias packing
        int idx = (b - 1092) * 256 + t;
        if (idx < 1344) {
            float v;
            if (idx < 192) v = bq[idx];
            else if (idx < 384) v = bsq[idx - 192];
            else if (idx < 768) v = bkv[idx - 384];
            else if (idx < 912) v = bqp[idx - 768];
            else v = bkvp[idx - 912];
            b1[idx] = v;
        } else if (idx < 1728) {
            int i2 = idx - 1344;
            b2[i2] = (i2 < 192) ? bsk[i2] : bsv[i2 - 192];
        }
        return;
    }
    const float* src; float* dst; int C, coff, tile, ldd;
    if (b < 72)       { src = Wq;   C = 192; dst = wt1; coff = 0;   ldd = 384;  tile = b; }
    else if (b < 144) { src = Wsq;  C = 192; dst = wt1; coff = 192; ldd = 384;  tile = b - 72; }
    else if (b < 288) { src = Wkv;  C = 384; dst = wt1; coff = 384; ldd = 384;  tile = b - 144; }
    else if (b < 348) { src = Wqp;  C = 144; dst = wt1; coff = 768; ldd = 384;  tile = b - 288; }
    else if (b < 516) { src = Wkvp; C = 432; dst = wt1; coff = 912; ldd = 384;  tile = b - 348; }
    else if (b < 588) { src = Wsk;  C = 192; dst = wt2; coff = 0;   ldd = 384;  tile = b - 516; }
    else if (b < 660) { src = Wsv;  C = 192; dst = wt2; coff = 192; ldd = 384;  tile = b - 588; }
    else              { src = Wout; C = 384; dst = wt3; coff = 0;   ldd = 1152; tile = b - 660; }
    const int cT = (C + 31) >> 5;
    const int tk = tile / cT, tc = tile % cT;
    __shared__ float l[32][33];
    const int tr = t >> 5, tcc = t & 31;
    #pragma unroll
    for (int rr = 0; rr < 4; ++rr) {
        int kloc = tr * 4 + rr;
        int cg = tc * 32 + tcc;
        l[kloc][tcc] = (cg < C) ? src[(size_t)(tk * 32 + kloc) * C + cg] : 0.f;
    }
    __syncthreads();
    #pragma unroll
    for (int rr = 0; rr < 4; ++rr) {
        int cloc = tr * 4 + rr;
        int cg = tc * 32 + cloc;
        if (cg < C) dst[(size_t)(coff + cg) * ldd + tk * 32 + tcc] = l[tcc][cloc];
    }
}

// ---------------------------------------------------------------- gemm
// C[M,N] = A[M,KTOT] @ Wt[N,KTOT]^T + bias. 64x64 tile, 256 thr (4 waves 2x2),
// thread = 4x4 outputs (rows/cols stride 8). LDS stride 68 -> conflict-free.
template<int KTOT>
__global__ __launch_bounds__(256) void k_gemm(
    const float* __restrict__ A, const float* __restrict__ Wt,
    const float* __restrict__ bias, float* __restrict__ C, int ldc)
{
    __shared__ float As[64][68];
    __shared__ float Ws[64][68];
    const int t = threadIdx.x;
    const int c0 = blockIdx.x * 64, m0 = blockIdx.y * 64;
    const int sr = t >> 4, sk4 = (t & 15) << 2;
    const int wid = t >> 6, lane = t & 63;
    const int wr = (wid >> 1) * 32, wc = (wid & 1) * 32;
    const int lr = lane >> 3, lc = lane & 7;
    float acc[4][4];
    #pragma unroll
    for (int j = 0; j < 4; ++j) {
        float bv = bias[c0 + wc + lc + 8 * j];
        #pragma unroll
        for (int i = 0; i < 4; ++i) acc[i][j] = bv;
    }
    for (int kc = 0; kc < KTOT; kc += 64) {
        __syncthreads();
        #pragma unroll
        for (int rep = 0; rep < 4; ++rep) {
            int row = sr + rep * 16;
            *(float4*)&As[row][sk4] = *(const float4*)&A[(size_t)(m0 + row) * KTOT + kc + sk4];
            *(float4*)&Ws[row][sk4] = *(const float4*)&Wt[(size_t)(c0 + row) * KTOT + kc + sk4];
        }
        __syncthreads();
        #pragma unroll 4
        for (int k4 = 0; k4 < 16; ++k4) {
            float4 a[4], w[4];
            #pragma unroll
            for (int i = 0; i < 4; ++i) a[i] = *(float4*)&As[wr + lr + 8 * i][k4 * 4];
            #pragma unroll
            for (int j = 0; j < 4; ++j) w[j] = *(float4*)&Ws[wc + lc + 8 * j][k4 * 4];
            #pragma unroll
            for (int i = 0; i < 4; ++i) {
                #pragma unroll
                for (int j = 0; j < 4; ++j) {
                    acc[i][j] = fmaf(a[i].x, w[j].x, acc[i][j]);
                    acc[i][j] = fmaf(a[i].y, w[j].y, acc[i][j]);
                    acc[i][j] = fmaf(a[i].z, w[j].z, acc[i][j]);
                    acc[i][j] = fmaf(a[i].w, w[j].w, acc[i][j]);
                }
            }
        }
    }
    #pragma unroll
    for (int i = 0; i < 4; ++i) {
        #pragma unroll
        for (int j = 0; j < 4; ++j)
            C[(size_t)(m0 + wr + lr + 8 * i) * ldc + c0 + wc + lc + 8 * j] = acc[i][j];
    }
}

// ---------------------------------------------------------------- scatter
__global__ __launch_bounds__(256) void k_scatter(
    const float* __restrict__ proj, const float* __restrict__ rots,
    const float* __restrict__ trans,
    float* __restrict__ qw, float* __restrict__ kw, float* __restrict__ vw,
    float* __restrict__ sqw, float* __restrict__ qpw, float* __restrict__ kpw,
    float* __restrict__ vpw)
{
    __shared__ float p[4][1344];
    const int n0 = blockIdx.x * 4, t = threadIdx.x;
    for (int idx = t; idx < 1344; idx += 256) {
        #pragma unroll
        for (int r = 0; r < 4; ++r) p[r][idx] = proj[(size_t)(n0 + r) * 1344 + idx];
    }
    __syncthreads();
    for (int idx = t; idx < 3072; idx += 256) {
        int r = idx / 768, c = idx % 768;
        int n = n0 + r;
        float v = p[r][c];
        if (c < 192) qw[(size_t)n * 192 + c] = v;
        else if (c < 384) sqw[(size_t)n * 192 + (c - 192)] = v;
        else {
            int cc = c - 384, h = cc >> 5, sub = cc & 31;
            if (sub < 16) kw[(size_t)n * 192 + h * 16 + sub] = v;
            else          vw[(size_t)n * 192 + h * 16 + (sub - 16)] = v;
        }
    }
    for (int idx = t; idx < 2304; idx += 256) {
        int r = idx / 576, rem = idx % 576;
        int n = n0 + r;
        const float* R = &rots[(size_t)n * 9];
        const float* tr = &trans[(size_t)n * 3];
        if (rem < 144) {
            int pp = rem / 3, d = rem % 3;
            float v = fmaf(R[d*3+0], p[r][768 + pp],
                      fmaf(R[d*3+1], p[r][768 + 48 + pp],
                      fmaf(R[d*3+2], p[r][768 + 96 + pp], tr[d])));
            qpw[(size_t)n * 144 + pp * 3 + d] = v;
        } else {
            int rem2 = rem - 144; int pp = rem2 / 3, d = rem2 % 3;
            float v = fmaf(R[d*3+0], p[r][912 + pp],
                      fmaf(R[d*3+1], p[r][912 + 144 + pp],
                      fmaf(R[d*3+2], p[r][912 + 288 + pp], tr[d])));
            int h = pp / 12, ii = pp % 12;
            if (ii < 4) kpw[(size_t)n * 144 + h * 12 + ii * 3 + d] = v;
            else        vpw[(size_t)n * 288 + h * 24 + (ii - 4) * 3 + d] = v;
        }
    }
}

// ---------------------------------------------------------------- sfeat
__global__ __launch_bounds__(256) void k_sfeat(
    const float* __restrict__ sf, const float* __restrict__ Wse,
    const float* __restrict__ bse, float* __restrict__ sfeat)
{
    __shared__ float wl[16 * 384];
    __shared__ float sfl[8][16];
    const int m0 = blockIdx.x * 8, t = threadIdx.x;
    for (int idx = t; idx < 6144; idx += 256) wl[idx] = Wse[idx];
    if (t < 128) sfl[t >> 4][t & 15] = sf[(size_t)(m0 + (t >> 4)) * 16 + (t & 15)];
    __syncthreads();
    #pragma unroll
    for (int u = 0; u < 12; ++u) {
        int idx = t + u * 256;
        int r = idx / 384, c = idx % 384;
        float a = bse[c];
        #pragma unroll
        for (int kk = 0; kk < 16; ++kk) a = fmaf(sfl[r][kk], wl[kk * 384 + c], a);
        sfeat[(size_t)(m0 + r) * 384 + c] = a;
    }
}

// ---------------------------------------------------------------- zpass
// bpz[i][c][j]: c<12 -> sqrt(1/3)*(z@Wb+bb)[h=c], c>=12 -> (z@Wdz+bdz)[c-12]
__global__ __launch_bounds__(256) void k_zpass(
    const float* __restrict__ z, const float* __restrict__ Wb, const float* __restrict__ bb,
    const float* __restrict__ Wdz, const float* __restrict__ bdz, float* __restrict__ bpz)
{
    __shared__ float Wt[44][128];
    __shared__ float bias_s[44];
    __shared__ float zt[64][132];
    const int i = blockIdx.x, t = threadIdx.x;
    const float s3 = 0.5773502691896258f;
    for (int idx = t; idx < 44 * 128; idx += 256) {
        int c = idx >> 7, kk = idx & 127;
        Wt[c][kk] = (c < 12) ? s3 * Wb[kk * 12 + c] : Wdz[kk * 32 + (c - 12)];
    }
    if (t < 44) bias_s[t] = (t < 12) ? s3 * bb[t] : bdz[t - 12];
    const int jl = t & 63, cg = t >> 6;
    for (int j0 = 0; j0 < 512; j0 += 64) {
        __syncthreads();
        for (int idx = t; idx < 2048; idx += 256) {
            int r = idx >> 5, c4 = (idx & 31) << 2;
            *(float4*)&zt[r][c4] = *(const float4*)&z[((size_t)i * 512 + j0 + r) * 128 + c4];
        }
        __syncthreads();
        float acc[11];
        #pragma unroll
        for (int u = 0; u < 11; ++u) acc[u] = bias_s[cg * 11 + u];
        #pragma unroll 2
        for (int k4 = 0; k4 < 128; k4 += 4) {
            float4 zv = *(float4*)&zt[jl][k4];
            #pragma unroll
            for (int u = 0; u < 11; ++u) {
                float4 wv = *(float4*)&Wt[cg * 11 + u][k4];
                acc[u] = fmaf(zv.x, wv.x, acc[u]);
                acc[u] = fmaf(zv.y, wv.y, acc[u]);
                acc[u] = fmaf(zv.z, wv.z, acc[u]);
                acc[u] = fmaf(zv.w, wv.w, acc[u]);
            }
        }
        #pragma unroll
        for (int u = 0; u < 11; ++u)
            bpz[((size_t)i * 44 + cg * 11 + u) * 512 + j0 + jl] = acc[u];
    }
}

// ---------------------------------------------------------------- attn
__global__ __launch_bounds__(256) void k_attn(
    const float* __restrict__ qw, const float* __restrict__ kw, const float* __restrict__ vw,
    const float* __restrict__ qpw, const float* __restrict__ kpw, const float* __restrict__ vpw,
    const float* __restrict__ bpz, const float* __restrict__ mask,
    const float* __restrict__ rots, const float* __restrict__ trans,
    const float* __restrict__ hwp, float* __restrict__ ocat)
{
    __shared__ float pls[12 * 516];
    __shared__ float qs[192], qps[144], opt[288], cpt[12], red[4];
    const int i = blockIdx.x, t = threadIdx.x;
    if (t < 192) qs[t] = qw[(size_t)i * 192 + t];
    if (t < 144) qps[t] = qpw[(size_t)i * 144 + t];
    if (t < 12) cpt[t] = -0.5f * 0.13608276348795434f * softplusf(hwp[t]);
    const float mask_i = mask[i];
    __syncthreads();
    for (int hj = t; hj < 6144; hj += 256) {
        int h = hj >> 9, j = hj & 511;
        float kj[16], kpj[12];
        { const float4* kr = (const float4*)&kw[(size_t)j * 192 + h * 16];
          *(float4*)&kj[0] = kr[0]; *(float4*)&kj[4] = kr[1];
          *(float4*)&kj[8] = kr[2]; *(float4*)&kj[12] = kr[3]; }
        { const float4* kr = (const float4*)&kpw[(size_t)j * 144 + h * 12];
          *(float4*)&kpj[0] = kr[0]; *(float4*)&kpj[4] = kr[1]; *(float4*)&kpj[8] = kr[2]; }
        float qk = 0.f;
        #pragma unroll
        for (int c = 0; c < 16; ++c) qk = fmaf(qs[h * 16 + c], kj[c], qk);
        float pts = 0.f;
        #pragma unroll
        for (int p = 0; p < 4; ++p) {
            float dx = qps[h*12+p*3+0] - kpj[p*3+0];
            float dy = qps[h*12+p*3+1] - kpj[p*3+1];
            float dz = qps[h*12+p*3+2] - kpj[p*3+2];
            pts += dx*dx + dy*dy + dz*dz;
        }
        float lg = fmaf(0.14433756729740643f, qk, bpz[((size_t)i * 44 + h) * 512 + j]);
        lg = fmaf(cpt[h], pts, lg);
        lg += INFV * (mask_i * mask[j] - 1.0f);
        pls[h * 516 + j] = lg;
    }
    __syncthreads();
    for (int h = 0; h < 12; ++h) {
        float v0 = pls[h * 516 + t], v1 = pls[h * 516 + 256 + t];
        float mx = fmaxf(v0, v1);
        #pragma unroll
        for (int off = 32; off; off >>= 1) mx = fmaxf(mx, __shfl_xor(mx, off));
        if ((t & 63) == 0) red[t >> 6] = mx;
        __syncthreads();
        mx = fmaxf(fmaxf(red[0], red[1]), fmaxf(red[2], red[3]));
        __syncthreads();
        float e0 = __expf(v0 - mx), e1 = __expf(v1 - mx);
        float sm = e0 + e1;
        #pragma unroll
        for (int off = 32; off; off >>= 1) sm += __shfl_xor(sm, off);
        if ((t & 63) == 0) red[t >> 6] = sm;
        __syncthreads();
        float inv = 1.0f / (red[0] + red[1] + red[2] + red[3]);
        pls[h * 516 + t] = e0 * inv;
        pls[h * 516 + 256 + t] = e1 * inv;
        __syncthreads();
    }
    for (int rnd = 0; rnd < 2; ++rnd) {
        int oi = t + rnd * 256;
        if (oi < 480) {
            int h, stride; const float* src;
            if (oi < 192) { h = oi >> 4; src = vw + oi; stride = 192; }
            else { h = (oi - 192) / 24; src = vpw + (oi - 192); stride = 288; }
            const float* pr = &pls[h * 516];
            float a0 = 0, a1 = 0, a2 = 0, a3 = 0;
            for (int j = 0; j < 512; j += 4) {
                a0 = fmaf(pr[j+0], src[(size_t)(j+0) * stride], a0);
                a1 = fmaf(pr[j+1], src[(size_t)(j+1) * stride], a1);
                a2 = fmaf(pr[j+2], src[(size_t)(j+2) * stride], a2);
                a3 = fmaf(pr[j+3], src[(size_t)(j+3) * stride], a3);
            }
            float acc = (a0 + a1) + (a2 + a3);
            if (oi < 192) ocat[(size_t)i * 1152 + oi] = acc;
            else opt[oi - 192] = acc;
        }
    }
    {
        int w = t >> 6, lane = t & 63;
        for (int u = 0; u < 96; ++u) {
            int oi = w * 96 + u; int h = oi >> 5, c = oi & 31;
            const float* pz = &bpz[((size_t)i * 44 + 12 + c) * 512];
            const float* pr = &pls[h * 516];
            float sacc = 0.f;
            #pragma unroll
            for (int jj = 0; jj < 8; ++jj)
                sacc = fmaf(pr[lane + jj * 64], pz[lane + jj * 64], sacc);
            #pragma unroll
            for (int off = 32; off; off >>= 1) sacc += __shfl_xor(sacc, off);
            if (lane == 0) ocat[(size_t)i * 1152 + 576 + oi] = sacc;
        }
    }
    __syncthreads();
    if (t < 96) {
        int h = t >> 3, p = t & 7;
        const float* R = &rots[(size_t)i * 9];
        float gx = opt[h*24 + p*3 + 0] - trans[(size_t)i*3 + 0];
        float gy = opt[h*24 + p*3 + 1] - trans[(size_t)i*3 + 1];
        float gz = opt[h*24 + p*3 + 2] - trans[(size_t)i*3 + 2];
        float lx = R[0]*gx + R[3]*gy + R[6]*gz;
        float ly = R[1]*gx + R[4]*gy + R[7]*gz;
        float lz = R[2]*gx + R[5]*gy + R[8]*gz;
        float nm = sqrtf(lx*lx + ly*ly + lz*lz + 1e-8f);
        int col = h * 8 + p;
        size_t base = (size_t)i * 1152;
        ocat[base + 192 + col] = lx;
        ocat[base + 288 + col] = ly;
        ocat[base + 384 + col] = lz;
        ocat[base + 480 + col] = nm;
    }
}

// ---------------------------------------------------------------- surf attn
__global__ __launch_bounds__(256) void k_surf(
    const float* __restrict__ sqw, const float* __restrict__ skv,
    const float* __restrict__ trans, const float* __restrict__ mask,
    const float* __restrict__ sp, const float* __restrict__ smask,
    const float* __restrict__ sbwp, float* __restrict__ ocat)
{
    __shared__ float sk_t[256][17];
    __shared__ float sv_t[256][17];
    __shared__ float sp_t[768];
    __shared__ float smask_t[256];
    const int h = blockIdx.x >> 5;
    const int n0 = (blockIdx.x & 31) * 16;
    const int t = threadIdx.x;
    const int tn = t >> 4, tm = t & 15;
    const int n = n0 + tn;
    const float sbw = softplusf(sbwp[0]);
    float qreg[16];
    #pragma unroll
    for (int c = 0; c < 16; ++c) qreg[c] = sqw[(size_t)n * 192 + h * 16 + c];
    const float trx = trans[(size_t)n*3+0], tryy = trans[(size_t)n*3+1], trz = trans[(size_t)n*3+2];
    const float mask_n = mask[n];
    float mx = -1e30f, l = 0.f;
    for (int tile = 0; tile < 8; ++tile) {
        __syncthreads();
        const int mb = tile * 256;
        for (int idx = t; idx < 1024; idx += 256) {
            int ml = idx >> 2, c4 = (idx & 3) << 2;
            float4 v4 = *(const float4*)&skv[(size_t)(mb + ml) * 384 + h * 16 + c4];
            sk_t[ml][c4+0]=v4.x; sk_t[ml][c4+1]=v4.y; sk_t[ml][c4+2]=v4.z; sk_t[ml][c4+3]=v4.w;
        }
        for (int idx = t; idx < 768; idx += 256) sp_t[idx] = sp[(size_t)mb * 3 + idx];
        smask_t[t] = smask[mb + t];
        __syncthreads();
        for (int kk = 0; kk < 16; ++kk) {
            int ml = tm + (kk << 4);
            float dot = 0.f;
            #pragma unroll
            for (int c = 0; c < 16; ++c) dot = fmaf(qreg[c], sk_t[ml][c], dot);
            float dx = trx - sp_t[ml*3+0], dy = tryy - sp_t[ml*3+1], dz = trz - sp_t[ml*3+2];
            float lg = fmaf(0.25f, dot, -0.5f * sbw * (dx*dx + dy*dy + dz*dz));
            lg += INFV * (mask_n * smask_t[ml] - 1.0f);
            float mn = fmaxf(mx, lg);
            l = l * __expf(mx - mn) + __expf(lg - mn);
            mx = mn;
        }
    }
    #pragma unroll
    for (int off = 1; off < 16; off <<= 1) {
        float m2 = __shfl_xor(mx, off), l2 = __shfl_xor(l, off);
        float mn = fmaxf(mx, m2);
        l = l * __expf(mx - mn) + l2 * __expf(m2 - mn);
        mx = mn;
    }
    const float invl = 1.0f / l;
    float acc[16];
    #pragma unroll
    for (int c = 0; c < 16; ++c) acc[c] = 0.f;
    for (int tile = 0; tile < 8; ++tile) {
        __syncthreads();
        const int mb = tile * 256;
        for (int idx = t; idx < 1024; idx += 256) {
            int ml = idx >> 2, c4 = (idx & 3) << 2;
            float4 v4 = *(const float4*)&skv[(size_t)(mb + ml) * 384 + h * 16 + c4];
            sk_t[ml][c4+0]=v4.x; sk_t[ml][c4+1]=v4.y; sk_t[ml][c4+2]=v4.z; sk_t[ml][c4+3]=v4.w;
            float4 w4 = *(const float4*)&skv[(size_t)(mb + ml) * 384 + 192 + h * 16 + c4];
            sv_t[ml][c4+0]=w4.x; sv_t[ml][c4+1]=w4.y; sv_t[ml][c4+2]=w4.z; sv_t[ml][c4+3]=w4.w;
        }
        for (int idx = t; idx < 768; idx += 256) sp_t[idx] = sp[(size_t)mb * 3 + idx];
        smask_t[t] = smask[mb + t];
        __syncthreads();
        for (int kk = 0; kk < 16; ++kk) {
            int ml = tm + (kk << 4);
            float dot = 0.f;
            #pragma unroll
            for (int c = 0; c < 16; ++c) dot = fmaf(qreg[c], sk_t[ml][c], dot);
            float dx = trx - sp_t[ml*3+0], dy = tryy - sp_t[ml*3+1], dz = trz - sp_t[ml*3+2];
            float lg = fmaf(0.25f, dot, -0.5f * sbw * (dx*dx + dy*dy + dz*dz));
            lg += INFV * (mask_n * smask_t[ml] - 1.0f);
            float w = __expf(lg - mx) * invl;
            #pragma unroll
            for (int c = 0; c < 16; ++c) acc[c] = fmaf(w, sv_t[ml][c], acc[c]);
        }
    }
    #pragma unroll
    for (int off = 1; off < 16; off <<= 1) {
        #pragma unroll
        for (int c = 0; c < 16; ++c) acc[c] += __shfl_xor(acc[c], off);
    }
    float outv = 0.f;
    #pragma unroll
    for (int c = 0; c < 16; ++c) if (tm == c) outv = acc[c];
    ocat[(size_t)n * 1152 + 960 + h * 16 + tm] = outv;
}

// ---------------------------------------------------------------- ts + s_agg
__global__ __launch_bounds__(256) void k_ts(
    const float* __restrict__ s, const float* __restrict__ sqw, const float* __restrict__ skv,
    const float* __restrict__ trans, const float* __restrict__ mask,
    const float* __restrict__ sp, const float* __restrict__ smask,
    const float* __restrict__ sbwp, float* __restrict__ saggw)
{
    __shared__ float big[32 * 384];
    __shared__ float sk_l[1536];
    __shared__ float w_lds[8][32];
    __shared__ float spm[24], smaskm[8];
    __shared__ float trans_t[96], mask_t[32];
    const int m0 = blockIdx.x * 8, t = threadIdx.x;
    const int tm = t >> 5, tn = t & 31;
    const float sbw = softplusf(sbwp[0]);
    for (int idx = t; idx < 1536; idx += 256) {
        int row = idx / 192, c = idx % 192;
        sk_l[idx] = skv[(size_t)(m0 + row) * 384 + c];
    }
    if (t < 24) spm[t] = sp[(size_t)m0 * 3 + t];
    if (t < 8) smaskm[t] = smask[m0 + t];
    __syncthreads();
    const float spx = spm[tm*3+0], spy = spm[tm*3+1], spz = spm[tm*3+2];
    const float smk = smaskm[tm];
    float mxr[12], lr[12];
    #pragma unroll
    for (int h = 0; h < 12; ++h) { mxr[h] = -1e30f; lr[h] = 0.f; }
    for (int tile = 0; tile < 16; ++tile) {
        __syncthreads();
        const int nb = tile * 32;
        for (int idx = t; idx < 1536; idx += 256) {
            int nn = idx / 48, c4 = (idx % 48) * 4;
            *(float4*)&big[nn * 196 + c4] = *(const float4*)&sqw[(size_t)(nb + nn) * 192 + c4];
        }
        if (t < 96) trans_t[t] = trans[(size_t)nb * 3 + t];
        if (t < 32) mask_t[t] = mask[nb + t];
        __syncthreads();
        float dx = spx - trans_t[tn*3+0], dy = spy - trans_t[tn*3+1], dz = spz - trans_t[tn*3+2];
        float mterm = INFV * (mask_t[tn] * smk - 1.0f) - 0.5f * sbw * (dx*dx + dy*dy + dz*dz);
        #pragma unroll
        for (int h = 0; h < 12; ++h) {
            float dot = 0.f;
            #pragma unroll
            for (int c = 0; c < 16; ++c)
                dot = fmaf(big[tn * 196 + h * 16 + c], sk_l[tm * 192 + h * 16 + c], dot);
            float lg = fmaf(0.25f, dot, mterm);
            float mn = fmaxf(mxr[h], lg);
            lr[h] = lr[h] * __expf(mxr[h] - mn) + __expf(lg - mn);
            mxr[h] = mn;
        }
    }
    #pragma unroll
    for (int h = 0; h < 12; ++h) {
        float mx = mxr[h], l = lr[h];
        #pragma unroll
        for (int off = 1; off < 32; off <<= 1) {
            float m2 = __shfl_xor(mx, off), l2 = __shfl_xor(l, off);
            float mn = fmaxf(mx, m2);
            l = l * __expf(mx - mn) + l2 * __expf(m2 - mn);
            mx = mn;
        }
        mxr[h] = mx; lr[h] = 1.0f / l;
    }
    float acc[12];
    #pragma unroll
    for (int u = 0; u < 12; ++u) acc[u] = 0.f;
    for (int tile = 0; tile < 16; ++tile) {
        __syncthreads();
        const int nb = tile * 32;
        for (int idx = t; idx < 1536; idx += 256) {
            int nn = idx / 48, c4 = (idx % 48) * 4;
            *(float4*)&big[nn * 196 + c4] = *(const float4*)&sqw[(size_t)(nb + nn) * 192 + c4];
        }
        if (t < 96) trans_t[t] = trans[(size_t)nb * 3 + t];
        if (t < 32) mask_t[t] = mask[nb + t];
        __syncthreads();
        {
            float dx = spx - trans_t[tn*3+0], dy = spy - trans_t[tn*3+1], dz = spz - trans_t[tn*3+2];
            float mterm = INFV * (mask_t[tn] * smk - 1.0f) - 0.5f * sbw * (dx*dx + dy*dy + dz*dz);
            float w = 0.f;
            #pragma unroll
            for (int h = 0; h < 12; ++h) {
                float dot = 0.f;
                #pragma unroll
                for (int c = 0; c < 16; ++c)
                    dot = fmaf(big[tn * 196 + h * 16 + c], sk_l[tm * 192 + h * 16 + c], dot);
                float lg = fmaf(0.25f, dot, mterm);
                w += __expf(lg - mxr[h]) * lr[h];
            }
            w_lds[tm][tn] = w * (1.0f / 12.0f);
        }
        __syncthreads();
        for (int idx = t; idx < 3072; idx += 256) {
            int nn = idx / 96, c4 = (idx % 96) * 4;
            *(float4*)&big[nn * 384 + c4] = *(const float4*)&s[(size_t)(nb + nn) * 384 + c4];
        }
        __syncthreads();
        for (int nn = 0; nn < 32; ++nn) {
            float wv = w_lds[tm][nn];
            #pragma unroll
            for (int u = 0; u < 12; ++u)
                acc[u] = fmaf(wv, big[nn * 384 + tn * 12 + u], acc[u]);
        }
    }
    #pragma unroll
    for (int u = 0; u < 12; ++u)
        saggw[(size_t)(m0 + tm) * 384 + tn * 12 + u] = acc[u];
}

// ---------------------------------------------------------------- surf out
__global__ __launch_bounds__(256) void k_surf_out(
    const float* __restrict__ sfeat, const float* __restrict__ saggw,
    const float* __restrict__ Wso, const float* __restrict__ bso,
    float* __restrict__ out)
{
    __shared__ float wl[12304];  // 4 k-blocks of 192*16 + pad 4
    const int t = threadIdx.x;
    for (int idx = t; idx < 12288; idx += 256) {
        int k = idx >> 4, c = idx & 15;
        wl[(k / 192) * 3076 + (k % 192) * 16 + c] = Wso[idx];
    }
    const int m = blockIdx.x * 64 + (t >> 2);
    const int kq = t & 3;
    const float* src = (kq < 2) ? &sfeat[(size_t)m * 384 + kq * 192]
                                : &saggw[(size_t)m * 384 + (kq - 2) * 192];
    __syncthreads();
    float acc[16];
    #pragma unroll
    for (int c = 0; c < 16; ++c) acc[c] = 0.f;
    const float* wb = &wl[kq * 3076];
    for (int k = 0; k < 192; k += 4) {
        float4 v = *(const float4*)&src[k];
        #pragma unroll
        for (int e = 0; e < 4; ++e) {
            float sv = (&v.x)[e];
            #pragma unroll
            for (int c = 0; c < 16; ++c)
                acc[c] = fmaf(sv, wb[(k + e) * 16 + c], acc[c]);
        }
    }
    #pragma unroll
    for (int c = 0; c < 16; ++c) {
        acc[c] += __shfl_xor(acc[c], 1);
        acc[c] += __shfl_xor(acc[c], 2);
    }
    #pragma unroll
    for (int c = 0; c < 16; ++c) {
        if ((c >> 2) == kq) out[196608 + (size_t)m * 16 + c] = acc[c] + bso[c];
    }
}

// ----------------------------------------------------------------
extern "C" void kernel_launch(void* const* d_in, const int* in_sizes, int n_in,
                              void* d_out, int out_size, void* d_ws, size_t ws_size,
                              hipStream_t stream)
{
    (void)in_sizes; (void)n_in; (void)out_size; (void)ws_size;
    const float* s     = (const float*)d_in[0];
    const float* z     = (const float*)d_in[1];
    const float* rots  = (const float*)d_in[2];
    const float* trans = (const float*)d_in[3];
    const float* mask  = (const float*)d_in[4];
    const float* sp    = (const float*)d_in[5];
    const float* sf    = (const float*)d_in[6];
    const float* smask = (const float*)d_in[7];
    const float* Wq    = (const float*)d_in[8];  const float* bq   = (const float*)d_in[9];
    const float* Wkv   = (const float*)d_in[10]; const float* bkv  = (const float*)d_in[11];
    const float* Wqp   = (const float*)d_in[12]; const float* bqp  = (const float*)d_in[13];
    const float* Wkvp  = (const float*)d_in[14]; const float* bkvp = (const float*)d_in[15];
    const float* Wse   = (const float*)d_in[16]; const float* bse  = (const float*)d_in[17];
    const float* Wsq   = (const float*)d_in[18]; const float* bsq  = (const float*)d_in[19];
    const float* Wsk   = (const float*)d_in[20]; const float* bsk  = (const float*)d_in[21];
    const float* Wsv   = (const float*)d_in[22]; const float* bsv  = (const float*)d_in[23];
    const float* Wb    = (const float*)d_in[24]; const float* bb   = (const float*)d_in[25];
    const float* Wdz   = (const float*)d_in[26]; const float* bdz  = (const float*)d_in[27];
    const float* hw    = (const float*)d_in[28]; const float* sbw  = (const float*)d_in[29];
    const float* Wout  = (const float*)d_in[30]; const float* bout = (const float*)d_in[31];
    const float* Wso   = (const float*)d_in[32]; const float* bso  = (const float*)d_in[33];
    float* out = (float*)d_out;

    float* qw    = (float*)d_ws;
    float* kw    = qw    + (size_t)512 * 192;
    float* vw    = kw    + (size_t)512 * 192;
    float* sqw   = vw    + (size_t)512 * 192;
    float* qpw   = sqw   + (size_t)512 * 192;
    float* kpw   = qpw   + (size_t)512 * 144;
    float* vpw   = kpw   + (size_t)512 * 144;
    float* sfeat = vpw   + (size_t)512 * 288;
    float* skv   = sfeat + (size_t)2048 * 384;
    float* ocat  = skv   + (size_t)2048 * 384;
    float* sagg  = ocat  + (size_t)512 * 1152;
    float* bpz   = sagg  + (size_t)2048 * 384;   // 512*44*512
    float* wt1   = bpz   + (size_t)512 * 44 * 512;
    float* wt2   = wt1   + (size_t)1344 * 384;
    float* wt3   = wt2   + (size_t)384 * 384;
    float* b1    = wt3   + (size_t)384 * 1152;
    float* b2    = b1    + 1344;
    // proj aliases bpz: proj is dead (consumed by k_scatter) before k_zpass
    // writes bpz, and kernels execute in stream order.
    float* proj  = bpz;

    k_pack<<<dim3(1099), dim3(256), 0, stream>>>(Wq, Wsq, Wkv, Wqp, Wkvp, Wsk, Wsv, Wout,
        bq, bsq, bkv, bqp, bkvp, bsk, bsv, wt1, wt2, wt3, b1, b2);
    k_gemm<384><<<dim3(21, 8), dim3(256), 0, stream>>>(s, wt1, b1, proj, 1344);
    k_scatter<<<dim3(128), dim3(256), 0, stream>>>(proj, rots, trans,
        qw, kw, vw, sqw, qpw, kpw, vpw);
    k_sfeat<<<dim3(256), dim3(256), 0, stream>>>(sf, Wse, bse, sfeat);
    k_gemm<384><<<dim3(6, 32), dim3(256), 0, stream>>>(sfeat, wt2, b2, skv, 384);
    k_zpass<<<dim3(512), dim3(256), 0, stream>>>(z, Wb, bb, Wdz, bdz, bpz);
    k_attn<<<dim3(512), dim3(256), 0, stream>>>(qw, kw, vw, qpw, kpw, vpw, bpz, mask,
        rots, trans, hw, ocat);
    k_surf<<<dim3(384), dim3(256), 0, stream>>>(sqw, skv, trans, mask, sp, smask,
        sbw, ocat);
    k_ts<<<dim3(256), dim3(256), 0, stream>>>(s, sqw, skv, trans, mask, sp, smask,
        sbw, sagg);
    k_surf_out<<<dim3(32), dim3(256), 0, stream>>>(sfeat, sagg, Wso, bso, out);
    k_gemm<1152><<<dim3(6, 8), dim3(256), 0, stream>>>(ocat, wt3, bout, out, 384);
}

// Round 3
// 524.262 us; speedup vs baseline: 1.8986x; 1.1856x over previous
//
#include <hip/hip_runtime.h>
#include <cstddef>

// IPA + surface cross-attention, B=1, N=512, M=2048, H=12, C_H=16, C_S=384.
// Round 2: k_ts (175us, latency-bound) -> k_tlog/k_tw/gemm pipeline;
// k_surf -> single-pass flash.

#define CS 384
#define INFV 100000.0f

__device__ __forceinline__ float softplusf(float x) { return log1pf(__expf(x)); }

// ---------------------------------------------------------------- pack
__global__ __launch_bounds__(256) void k_pack(
    const float* __restrict__ Wq, const float* __restrict__ Wsq,
    const float* __restrict__ Wkv, const float* __restrict__ Wqp,
    const float* __restrict__ Wkvp, const float* __restrict__ Wsk,
    const float* __restrict__ Wsv, const float* __restrict__ Wout,
    const float* __restrict__ bq, const float* __restrict__ bsq,
    const float* __restrict__ bkv, const float* __restrict__ bqp,
    const float* __restrict__ bkvp, const float* __restrict__ bsk,
    const float* __restrict__ bsv,
    float* __restrict__ wt1, float* __restrict__ wt2, float* __restrict__ wt3,
    float* __restrict__ b1, float* __restrict__ b2)
{
    const int b = blockIdx.x, t = threadIdx.x;
    if (b >= 1092) {  // bias packing
        int idx = (b - 1092) * 256 + t;
        if (idx < 1344) {
            float v;
            if (idx < 192) v = bq[idx];
            else if (idx < 384) v = bsq[idx - 192];
            else if (idx < 768) v = bkv[idx - 384];
            else if (idx < 912) v = bqp[idx - 768];
            else v = bkvp[idx - 912];
            b1[idx] = v;
        } else if (idx < 1728) {
            int i2 = idx - 1344;
            b2[i2] = (i2 < 192) ? bsk[i2] : bsv[i2 - 192];
        }
        return;
    }
    const float* src; float* dst; int C, coff, tile, ldd;
    if (b < 72)       { src = Wq;   C = 192; dst = wt1; coff = 0;   ldd = 384;  tile = b; }
    else if (b < 144) { src = Wsq;  C = 192; dst = wt1; coff = 192; ldd = 384;  tile = b - 72; }
    else if (b < 288) { src = Wkv;  C = 384; dst = wt1; coff = 384; ldd = 384;  tile = b - 144; }
    else if (b < 348) { src = Wqp;  C = 144; dst = wt1; coff = 768; ldd = 384;  tile = b - 288; }
    else if (b < 516) { src = Wkvp; C = 432; dst = wt1; coff = 912; ldd = 384;  tile = b - 348; }
    else if (b < 588) { src = Wsk;  C = 192; dst = wt2; coff = 0;   ldd = 384;  tile = b - 516; }
    else if (b < 660) { src = Wsv;  C = 192; dst = wt2; coff = 192; ldd = 384;  tile = b - 588; }
    else              { src = Wout; C = 384; dst = wt3; coff = 0;   ldd = 1152; tile = b - 660; }
    const int cT = (C + 31) >> 5;
    const int tk = tile / cT, tc = tile % cT;
    __shared__ float l[32][33];
    const int tr = t >> 5, tcc = t & 31;
    #pragma unroll
    for (int rr = 0; rr < 4; ++rr) {
        int kloc = tr * 4 + rr;
        int cg = tc * 32 + tcc;
        l[kloc][tcc] = (cg < C) ? src[(size_t)(tk * 32 + kloc) * C + cg] : 0.f;
    }
    __syncthreads();
    #pragma unroll
    for (int rr = 0; rr < 4; ++rr) {
        int cloc = tr * 4 + rr;
        int cg = tc * 32 + cloc;
        if (cg < C) dst[(size_t)(coff + cg) * ldd + tk * 32 + tcc] = l[tcc][cloc];
    }
}

// ---------------------------------------------------------------- transpose
// At[C=384][R=512] from A[R=512][C=384]
__global__ __launch_bounds__(256) void k_transp(
    const float* __restrict__ A, float* __restrict__ At)
{
    __shared__ float tile[32][33];
    const int r0 = blockIdx.y * 32, c0 = blockIdx.x * 32;
    const int tr = threadIdx.x >> 5, tc = threadIdx.x & 31;
    #pragma unroll
    for (int rr = 0; rr < 4; ++rr)
        tile[tr + rr * 8][tc] = A[(size_t)(r0 + tr + rr * 8) * 384 + c0 + tc];
    __syncthreads();
    #pragma unroll
    for (int rr = 0; rr < 4; ++rr)
        At[(size_t)(c0 + tr + rr * 8) * 512 + r0 + tc] = tile[tc][tr + rr * 8];
}

// ---------------------------------------------------------------- gemm
template<int KTOT, bool HB>
__global__ __launch_bounds__(256) void k_gemm(
    const float* __restrict__ A, const float* __restrict__ Wt,
    const float* __restrict__ bias, float* __restrict__ C, int ldc)
{
    __shared__ float As[64][68];
    __shared__ float Ws[64][68];
    const int t = threadIdx.x;
    const int c0 = blockIdx.x * 64, m0 = blockIdx.y * 64;
    const int sr = t >> 4, sk4 = (t & 15) << 2;
    const int wid = t >> 6, lane = t & 63;
    const int wr = (wid >> 1) * 32, wc = (wid & 1) * 32;
    const int lr = lane >> 3, lc = lane & 7;
    float acc[4][4];
    #pragma unroll
    for (int j = 0; j < 4; ++j) {
        float bv = HB ? bias[c0 + wc + lc + 8 * j] : 0.f;
        #pragma unroll
        for (int i = 0; i < 4; ++i) acc[i][j] = bv;
    }
    for (int kc = 0; kc < KTOT; kc += 64) {
        __syncthreads();
        #pragma unroll
        for (int rep = 0; rep < 4; ++rep) {
            int row = sr + rep * 16;
            *(float4*)&As[row][sk4] = *(const float4*)&A[(size_t)(m0 + row) * KTOT + kc + sk4];
            *(float4*)&Ws[row][sk4] = *(const float4*)&Wt[(size_t)(c0 + row) * KTOT + kc + sk4];
        }
        __syncthreads();
        #pragma unroll 4
        for (int k4 = 0; k4 < 16; ++k4) {
            float4 a[4], w[4];
            #pragma unroll
            for (int i = 0; i < 4; ++i) a[i] = *(float4*)&As[wr + lr + 8 * i][k4 * 4];
            #pragma unroll
            for (int j = 0; j < 4; ++j) w[j] = *(float4*)&Ws[wc + lc + 8 * j][k4 * 4];
            #pragma unroll
            for (int i = 0; i < 4; ++i) {
                #pragma unroll
                for (int j = 0; j < 4; ++j) {
                    acc[i][j] = fmaf(a[i].x, w[j].x, acc[i][j]);
                    acc[i][j] = fmaf(a[i].y, w[j].y, acc[i][j]);
                    acc[i][j] = fmaf(a[i].z, w[j].z, acc[i][j]);
                    acc[i][j] = fmaf(a[i].w, w[j].w, acc[i][j]);
                }
            }
        }
    }
    #pragma unroll
    for (int i = 0; i < 4; ++i) {
        #pragma unroll
        for (int j = 0; j < 4; ++j)
            C[(size_t)(m0 + wr + lr + 8 * i) * ldc + c0 + wc + lc + 8 * j] = acc[i][j];
    }
}

// ---------------------------------------------------------------- scatter
__global__ __launch_bounds__(256) void k_scatter(
    const float* __restrict__ proj, const float* __restrict__ rots,
    const float* __restrict__ trans,
    float* __restrict__ qw, float* __restrict__ kw, float* __restrict__ vw,
    float* __restrict__ sqw, float* __restrict__ qpw, float* __restrict__ kpw,
    float* __restrict__ vpw)
{
    __shared__ float p[4][1344];
    const int n0 = blockIdx.x * 4, t = threadIdx.x;
    for (int idx = t; idx < 1344; idx += 256) {
        #pragma unroll
        for (int r = 0; r < 4; ++r) p[r][idx] = proj[(size_t)(n0 + r) * 1344 + idx];
    }
    __syncthreads();
    for (int idx = t; idx < 3072; idx += 256) {
        int r = idx / 768, c = idx % 768;
        int n = n0 + r;
        float v = p[r][c];
        if (c < 192) qw[(size_t)n * 192 + c] = v;
        else if (c < 384) sqw[(size_t)n * 192 + (c - 192)] = v;
        else {
            int cc = c - 384, h = cc >> 5, sub = cc & 31;
            if (sub < 16) kw[(size_t)n * 192 + h * 16 + sub] = v;
            else          vw[(size_t)n * 192 + h * 16 + (sub - 16)] = v;
        }
    }
    for (int idx = t; idx < 2304; idx += 256) {
        int r = idx / 576, rem = idx % 576;
        int n = n0 + r;
        const float* R = &rots[(size_t)n * 9];
        const float* tr = &trans[(size_t)n * 3];
        if (rem < 144) {
            int pp = rem / 3, d = rem % 3;
            float v = fmaf(R[d*3+0], p[r][768 + pp],
                      fmaf(R[d*3+1], p[r][768 + 48 + pp],
                      fmaf(R[d*3+2], p[r][768 + 96 + pp], tr[d])));
            qpw[(size_t)n * 144 + pp * 3 + d] = v;
        } else {
            int rem2 = rem - 144; int pp = rem2 / 3, d = rem2 % 3;
            float v = fmaf(R[d*3+0], p[r][912 + pp],
                      fmaf(R[d*3+1], p[r][912 + 144 + pp],
                      fmaf(R[d*3+2], p[r][912 + 288 + pp], tr[d])));
            int h = pp / 12, ii = pp % 12;
            if (ii < 4) kpw[(size_t)n * 144 + h * 12 + ii * 3 + d] = v;
            else        vpw[(size_t)n * 288 + h * 24 + (ii - 4) * 3 + d] = v;
        }
    }
}

// ---------------------------------------------------------------- sfeat
__global__ __launch_bounds__(256) void k_sfeat(
    const float* __restrict__ sf, const float* __restrict__ Wse,
    const float* __restrict__ bse, float* __restrict__ sfeat)
{
    __shared__ float wl[16 * 384];
    __shared__ float sfl[8][16];
    const int m0 = blockIdx.x * 8, t = threadIdx.x;
    for (int idx = t; idx < 6144; idx += 256) wl[idx] = Wse[idx];
    if (t < 128) sfl[t >> 4][t & 15] = sf[(size_t)(m0 + (t >> 4)) * 16 + (t & 15)];
    __syncthreads();
    #pragma unroll
    for (int u = 0; u < 12; ++u) {
        int idx = t + u * 256;
        int r = idx / 384, c = idx % 384;
        float a = bse[c];
        #pragma unroll
        for (int kk = 0; kk < 16; ++kk) a = fmaf(sfl[r][kk], wl[kk * 384 + c], a);
        sfeat[(size_t)(m0 + r) * 384 + c] = a;
    }
}

// ---------------------------------------------------------------- zpass
__global__ __launch_bounds__(256) void k_zpass(
    const float* __restrict__ z, const float* __restrict__ Wb, const float* __restrict__ bb,
    const float* __restrict__ Wdz, const float* __restrict__ bdz, float* __restrict__ bpz)
{
    __shared__ float Wt[44][128];
    __shared__ float bias_s[44];
    __shared__ float zt[64][132];
    const int i = blockIdx.x, t = threadIdx.x;
    const float s3 = 0.5773502691896258f;
    for (int idx = t; idx < 44 * 128; idx += 256) {
        int c = idx >> 7, kk = idx & 127;
        Wt[c][kk] = (c < 12) ? s3 * Wb[kk * 12 + c] : Wdz[kk * 32 + (c - 12)];
    }
    if (t < 44) bias_s[t] = (t < 12) ? s3 * bb[t] : bdz[t - 12];
    const int jl = t & 63, cg = t >> 6;
    for (int j0 = 0; j0 < 512; j0 += 64) {
        __syncthreads();
        for (int idx = t; idx < 2048; idx += 256) {
            int r = idx >> 5, c4 = (idx & 31) << 2;
            *(float4*)&zt[r][c4] = *(const float4*)&z[((size_t)i * 512 + j0 + r) * 128 + c4];
        }
        __syncthreads();
        float acc[11];
        #pragma unroll
        for (int u = 0; u < 11; ++u) acc[u] = bias_s[cg * 11 + u];
        #pragma unroll 2
        for (int k4 = 0; k4 < 128; k4 += 4) {
            float4 zv = *(float4*)&zt[jl][k4];
            #pragma unroll
            for (int u = 0; u < 11; ++u) {
                float4 wv = *(float4*)&Wt[cg * 11 + u][k4];
                acc[u] = fmaf(zv.x, wv.x, acc[u]);
                acc[u] = fmaf(zv.y, wv.y, acc[u]);
                acc[u] = fmaf(zv.z, wv.z, acc[u]);
                acc[u] = fmaf(zv.w, wv.w, acc[u]);
            }
        }
        #pragma unroll
        for (int u = 0; u < 11; ++u)
            bpz[((size_t)i * 44 + cg * 11 + u) * 512 + j0 + jl] = acc[u];
    }
}

// ---------------------------------------------------------------- attn
__global__ __launch_bounds__(256) void k_attn(
    const float* __restrict__ qw, const float* __restrict__ kw, const float* __restrict__ vw,
    const float* __restrict__ qpw, const float* __restrict__ kpw, const float* __restrict__ vpw,
    const float* __restrict__ bpz, const float* __restrict__ mask,
    const float* __restrict__ rots, const float* __restrict__ trans,
    const float* __restrict__ hwp, float* __restrict__ ocat)
{
    __shared__ float pls[12 * 516];
    __shared__ float qs[192], qps[144], opt[288], cpt[12], red[4];
    const int i = blockIdx.x, t = threadIdx.x;
    if (t < 192) qs[t] = qw[(size_t)i * 192 + t];
    if (t < 144) qps[t] = qpw[(size_t)i * 144 + t];
    if (t < 12) cpt[t] = -0.5f * 0.13608276348795434f * softplusf(hwp[t]);
    const float mask_i = mask[i];
    __syncthreads();
    for (int hj = t; hj < 6144; hj += 256) {
        int h = hj >> 9, j = hj & 511;
        float kj[16], kpj[12];
        { const float4* kr = (const float4*)&kw[(size_t)j * 192 + h * 16];
          *(float4*)&kj[0] = kr[0]; *(float4*)&kj[4] = kr[1];
          *(float4*)&kj[8] = kr[2]; *(float4*)&kj[12] = kr[3]; }
        { const float4* kr = (const float4*)&kpw[(size_t)j * 144 + h * 12];
          *(float4*)&kpj[0] = kr[0]; *(float4*)&kpj[4] = kr[1]; *(float4*)&kpj[8] = kr[2]; }
        float qk = 0.f;
        #pragma unroll
        for (int c = 0; c < 16; ++c) qk = fmaf(qs[h * 16 + c], kj[c], qk);
        float pts = 0.f;
        #pragma unroll
        for (int p = 0; p < 4; ++p) {
            float dx = qps[h*12+p*3+0] - kpj[p*3+0];
            float dy = qps[h*12+p*3+1] - kpj[p*3+1];
            float dz = qps[h*12+p*3+2] - kpj[p*3+2];
            pts += dx*dx + dy*dy + dz*dz;
        }
        float lg = fmaf(0.14433756729740643f, qk, bpz[((size_t)i * 44 + h) * 512 + j]);
        lg = fmaf(cpt[h], pts, lg);
        lg += INFV * (mask_i * mask[j] - 1.0f);
        pls[h * 516 + j] = lg;
    }
    __syncthreads();
    for (int h = 0; h < 12; ++h) {
        float v0 = pls[h * 516 + t], v1 = pls[h * 516 + 256 + t];
        float mx = fmaxf(v0, v1);
        #pragma unroll
        for (int off = 32; off; off >>= 1) mx = fmaxf(mx, __shfl_xor(mx, off));
        if ((t & 63) == 0) red[t >> 6] = mx;
        __syncthreads();
        mx = fmaxf(fmaxf(red[0], red[1]), fmaxf(red[2], red[3]));
        __syncthreads();
        float e0 = __expf(v0 - mx), e1 = __expf(v1 - mx);
        float sm = e0 + e1;
        #pragma unroll
        for (int off = 32; off; off >>= 1) sm += __shfl_xor(sm, off);
        if ((t & 63) == 0) red[t >> 6] = sm;
        __syncthreads();
        float inv = 1.0f / (red[0] + red[1] + red[2] + red[3]);
        pls[h * 516 + t] = e0 * inv;
        pls[h * 516 + 256 + t] = e1 * inv;
        __syncthreads();
    }
    for (int rnd = 0; rnd < 2; ++rnd) {
        int oi = t + rnd * 256;
        if (oi < 480) {
            int h, stride; const float* src;
            if (oi < 192) { h = oi >> 4; src = vw + oi; stride = 192; }
            else { h = (oi - 192) / 24; src = vpw + (oi - 192); stride = 288; }
            const float* pr = &pls[h * 516];
            float a0 = 0, a1 = 0, a2 = 0, a3 = 0;
            for (int j = 0; j < 512; j += 4) {
                a0 = fmaf(pr[j+0], src[(size_t)(j+0) * stride], a0);
                a1 = fmaf(pr[j+1], src[(size_t)(j+1) * stride], a1);
                a2 = fmaf(pr[j+2], src[(size_t)(j+2) * stride], a2);
                a3 = fmaf(pr[j+3], src[(size_t)(j+3) * stride], a3);
            }
            float acc = (a0 + a1) + (a2 + a3);
            if (oi < 192) ocat[(size_t)i * 1152 + oi] = acc;
            else opt[oi - 192] = acc;
        }
    }
    {
        int w = t >> 6, lane = t & 63;
        for (int u = 0; u < 96; ++u) {
            int oi = w * 96 + u; int h = oi >> 5, c = oi & 31;
            const float* pz = &bpz[((size_t)i * 44 + 12 + c) * 512];
            const float* pr = &pls[h * 516];
            float sacc = 0.f;
            #pragma unroll
            for (int jj = 0; jj < 8; ++jj)
                sacc = fmaf(pr[lane + jj * 64], pz[lane + jj * 64], sacc);
            #pragma unroll
            for (int off = 32; off; off >>= 1) sacc += __shfl_xor(sacc, off);
            if (lane == 0) ocat[(size_t)i * 1152 + 576 + oi] = sacc;
        }
    }
    __syncthreads();
    if (t < 96) {
        int h = t >> 3, p = t & 7;
        const float* R = &rots[(size_t)i * 9];
        float gx = opt[h*24 + p*3 + 0] - trans[(size_t)i*3 + 0];
        float gy = opt[h*24 + p*3 + 1] - trans[(size_t)i*3 + 1];
        float gz = opt[h*24 + p*3 + 2] - trans[(size_t)i*3 + 2];
        float lx = R[0]*gx + R[3]*gy + R[6]*gz;
        float ly = R[1]*gx + R[4]*gy + R[7]*gz;
        float lz = R[2]*gx + R[5]*gy + R[8]*gz;
        float nm = sqrtf(lx*lx + ly*ly + lz*lz + 1e-8f);
        int col = h * 8 + p;
        size_t base = (size_t)i * 1152;
        ocat[base + 192 + col] = lx;
        ocat[base + 288 + col] = ly;
        ocat[base + 384 + col] = lz;
        ocat[base + 480 + col] = nm;
    }
}

// ---------------------------------------------------------------- surf attn (single-pass flash)
__global__ __launch_bounds__(256) void k_surf(
    const float* __restrict__ sqw, const float* __restrict__ skv,
    const float* __restrict__ trans, const float* __restrict__ mask,
    const float* __restrict__ sp, const float* __restrict__ smask,
    const float* __restrict__ sbwp, float* __restrict__ ocat)
{
    __shared__ float sk_t[256][17];
    __shared__ float sv_t[256][17];
    __shared__ float sp_t[768];
    __shared__ float smask_t[256];
    const int h = blockIdx.x >> 5;
    const int n0 = (blockIdx.x & 31) * 16;
    const int t = threadIdx.x;
    const int tn = t >> 4, tm = t & 15;
    const int n = n0 + tn;
    const float sbw = softplusf(sbwp[0]);
    float qreg[16];
    #pragma unroll
    for (int c = 0; c < 16; ++c) qreg[c] = sqw[(size_t)n * 192 + h * 16 + c];
    const float trx = trans[(size_t)n*3+0], tryy = trans[(size_t)n*3+1], trz = trans[(size_t)n*3+2];
    const float mask_n = mask[n];
    float mx = -1e30f, l = 0.f;
    float acc[16];
    #pragma unroll
    for (int c = 0; c < 16; ++c) acc[c] = 0.f;
    for (int tile = 0; tile < 8; ++tile) {
        __syncthreads();
        const int mb = tile * 256;
        for (int idx = t; idx < 1024; idx += 256) {
            int ml = idx >> 2, c4 = (idx & 3) << 2;
            float4 v4 = *(const float4*)&skv[(size_t)(mb + ml) * 384 + h * 16 + c4];
            sk_t[ml][c4+0]=v4.x; sk_t[ml][c4+1]=v4.y; sk_t[ml][c4+2]=v4.z; sk_t[ml][c4+3]=v4.w;
            float4 w4 = *(const float4*)&skv[(size_t)(mb + ml) * 384 + 192 + h * 16 + c4];
            sv_t[ml][c4+0]=w4.x; sv_t[ml][c4+1]=w4.y; sv_t[ml][c4+2]=w4.z; sv_t[ml][c4+3]=w4.w;
        }
        for (int idx = t; idx < 768; idx += 256) sp_t[idx] = sp[(size_t)mb * 3 + idx];
        smask_t[t] = smask[mb + t];
        __syncthreads();
        float lgr[16];
        float tmax = -1e30f;
        #pragma unroll
        for (int kk = 0; kk < 16; ++kk) {
            int ml = tm + (kk << 4);
            float dot = 0.f;
            #pragma unroll
            for (int c = 0; c < 16; ++c) dot = fmaf(qreg[c], sk_t[ml][c], dot);
            float dx = trx - sp_t[ml*3+0], dy = tryy - sp_t[ml*3+1], dz = trz - sp_t[ml*3+2];
            float lg = fmaf(0.25f, dot, -0.5f * sbw * (dx*dx + dy*dy + dz*dz));
            lg += INFV * (mask_n * smask_t[ml] - 1.0f);
            lgr[kk] = lg;
            tmax = fmaxf(tmax, lg);
        }
        float mn = fmaxf(mx, tmax);
        float scale = __expf(mx - mn);
        l *= scale;
        #pragma unroll
        for (int c = 0; c < 16; ++c) acc[c] *= scale;
        #pragma unroll
        for (int kk = 0; kk < 16; ++kk) {
            int ml = tm + (kk << 4);
            float w = __expf(lgr[kk] - mn);
            l += w;
            #pragma unroll
            for (int c = 0; c < 16; ++c) acc[c] = fmaf(w, sv_t[ml][c], acc[c]);
        }
        mx = mn;
    }
    // combine across the 16 tm-lanes (bits 0-3 of lane)
    #pragma unroll
    for (int off = 1; off < 16; off <<= 1) {
        float m2 = __shfl_xor(mx, off), l2 = __shfl_xor(l, off);
        float mn = fmaxf(mx, m2);
        float e1 = __expf(mx - mn), e2 = __expf(m2 - mn);
        l = l * e1 + l2 * e2;
        #pragma unroll
        for (int c = 0; c < 16; ++c) {
            float a2 = __shfl_xor(acc[c], off);
            acc[c] = acc[c] * e1 + a2 * e2;
        }
        mx = mn;
    }
    const float invl = 1.0f / l;
    float outv = 0.f;
    #pragma unroll
    for (int c = 0; c < 16; ++c) if (tm == c) outv = acc[c];
    ocat[(size_t)n * 1152 + 960 + h * 16 + tm] = outv * invl;
}

// ---------------------------------------------------------------- tlog
// logits[m][h][n] (raw, incl. mask+dist terms) + per-(m,h) max & 1/sum.
__global__ __launch_bounds__(256) void k_tlog(
    const float* __restrict__ sqw, const float* __restrict__ skv,
    const float* __restrict__ trans, const float* __restrict__ mask,
    const float* __restrict__ sp, const float* __restrict__ smask,
    const float* __restrict__ sbwp, float* __restrict__ logits,
    float* __restrict__ stat_m, float* __restrict__ stat_il)
{
    __shared__ float sk_s[32][16];
    __shared__ float sq_s[32][16];
    __shared__ float trans_s[96];
    __shared__ float mask_s[32];
    __shared__ float spm_s[96];
    __shared__ float smask_s[32];
    const int h = blockIdx.y;
    const int m0 = blockIdx.x * 32;
    const int t = threadIdx.x;
    const int tmg = t >> 5, tnl = t & 31;
    const float sbw = softplusf(sbwp[0]);
    for (int idx = t; idx < 512; idx += 256) {
        int row = idx >> 4, c = idx & 15;
        sk_s[row][c] = skv[(size_t)(m0 + row) * 384 + h * 16 + c];
    }
    if (t < 96) spm_s[t] = sp[(size_t)m0 * 3 + t];
    if (t < 32) smask_s[t] = smask[m0 + t];
    __syncthreads();
    float skr[4][16];
    float spx[4], spy[4], spz[4], smk[4];
    #pragma unroll
    for (int mi = 0; mi < 4; ++mi) {
        int row = tmg * 4 + mi;
        #pragma unroll
        for (int c4 = 0; c4 < 16; c4 += 4)
            *(float4*)&skr[mi][c4] = *(float4*)&sk_s[row][c4];
        spx[mi] = spm_s[row*3+0]; spy[mi] = spm_s[row*3+1]; spz[mi] = spm_s[row*3+2];
        smk[mi] = smask_s[row];
    }
    float mxr[4], lr[4];
    #pragma unroll
    for (int mi = 0; mi < 4; ++mi) { mxr[mi] = -1e30f; lr[mi] = 0.f; }
    for (int nt = 0; nt < 16; ++nt) {
        __syncthreads();
        const int nb = nt * 32;
        if (t < 128) {
            int nn = t >> 2, c4 = (t & 3) << 2;
            *(float4*)&sq_s[nn][c4] = *(const float4*)&sqw[(size_t)(nb + nn) * 192 + h * 16 + c4];
        }
        if (t < 96) trans_s[t] = trans[(size_t)nb * 3 + t];
        if (t < 32) mask_s[t] = mask[nb + t];
        __syncthreads();
        float q[16];
        #pragma unroll
        for (int c4 = 0; c4 < 16; c4 += 4)
            *(float4*)&q[c4] = *(float4*)&sq_s[tnl][c4];
        const float tx = trans_s[tnl*3+0], ty = trans_s[tnl*3+1], tz = trans_s[tnl*3+2];
        const float mkn = mask_s[tnl];
        #pragma unroll
        for (int mi = 0; mi < 4; ++mi) {
            float dot = 0.f;
            #pragma unroll
            for (int c = 0; c < 16; ++c) dot = fmaf(skr[mi][c], q[c], dot);
            float dx = tx - spx[mi], dy = ty - spy[mi], dz = tz - spz[mi];
            float mterm = INFV * (mkn * smk[mi] - 1.0f) - 0.5f * sbw * (dx*dx + dy*dy + dz*dz);
            float lg = fmaf(0.25f, dot, mterm);
            logits[((size_t)(m0 + tmg * 4 + mi) * 12 + h) * 512 + nb + tnl] = lg;
            float newm = fmaxf(mxr[mi], lg);
            lr[mi] = lr[mi] * __expf(mxr[mi] - newm) + __expf(lg - newm);
            mxr[mi] = newm;
        }
    }
    #pragma unroll
    for (int off = 1; off < 32; off <<= 1) {
        #pragma unroll
        for (int mi = 0; mi < 4; ++mi) {
            float m2 = __shfl_xor(mxr[mi], off), l2 = __shfl_xor(lr[mi], off);
            float newm = fmaxf(mxr[mi], m2);
            lr[mi] = lr[mi] * __expf(mxr[mi] - newm) + l2 * __expf(m2 - newm);
            mxr[mi] = newm;
        }
    }
    if (tnl == 0) {
        #pragma unroll
        for (int mi = 0; mi < 4; ++mi) {
            int m = m0 + tmg * 4 + mi;
            stat_m[(size_t)m * 12 + h] = mxr[mi];
            stat_il[(size_t)m * 12 + h] = 1.0f / lr[mi];
        }
    }
}

// ---------------------------------------------------------------- tw
// w[m][n] = (1/12) sum_h exp(logits[m][h][n] - mx[m][h]) * il[m][h]
__global__ __launch_bounds__(256) void k_tw(
    const float* __restrict__ logits, const float* __restrict__ stat_m,
    const float* __restrict__ stat_il, float* __restrict__ w)
{
    __shared__ float mxs[12], ils[12];
    const int m = blockIdx.x, t = threadIdx.x;
    if (t < 12) { mxs[t] = stat_m[(size_t)m * 12 + t]; ils[t] = stat_il[(size_t)m * 12 + t]; }
    __syncthreads();
    const float* lp = logits + (size_t)m * 12 * 512;
    float a0 = 0.f, a1 = 0.f;
    #pragma unroll
    for (int h = 0; h < 12; ++h) {
        a0 += __expf(lp[h * 512 + t] - mxs[h]) * ils[h];
        a1 += __expf(lp[h * 512 + 256 + t] - mxs[h]) * ils[h];
    }
    w[(size_t)m * 512 + t] = a0 * (1.0f / 12.0f);
    w[(size_t)m * 512 + 256 + t] = a1 * (1.0f / 12.0f);
}

// ---------------------------------------------------------------- surf out
__global__ __launch_bounds__(256) void k_surf_out(
    const float* __restrict__ sfeat, const float* __restrict__ saggw,
    const float* __restrict__ Wso, const float* __restrict__ bso,
    float* __restrict__ out)
{
    __shared__ float wl[12304];
    const int t = threadIdx.x;
    for (int idx = t; idx < 12288; idx += 256) {
        int k = idx >> 4, c = idx & 15;
        wl[(k / 192) * 3076 + (k % 192) * 16 + c] = Wso[idx];
    }
    const int m = blockIdx.x * 64 + (t >> 2);
    const int kq = t & 3;
    const float* src = (kq < 2) ? &sfeat[(size_t)m * 384 + kq * 192]
                                : &saggw[(size_t)m * 384 + (kq - 2) * 192];
    __syncthreads();
    float acc[16];
    #pragma unroll
    for (int c = 0; c < 16; ++c) acc[c] = 0.f;
    const float* wb = &wl[kq * 3076];
    for (int k = 0; k < 192; k += 4) {
        float4 v = *(const float4*)&src[k];
        #pragma unroll
        for (int e = 0; e < 4; ++e) {
            float sv = (&v.x)[e];
            #pragma unroll
            for (int c = 0; c < 16; ++c)
                acc[c] = fmaf(sv, wb[(k + e) * 16 + c], acc[c]);
        }
    }
    #pragma unroll
    for (int c = 0; c < 16; ++c) {
        acc[c] += __shfl_xor(acc[c], 1);
        acc[c] += __shfl_xor(acc[c], 2);
    }
    #pragma unroll
    for (int c = 0; c < 16; ++c) {
        if ((c >> 2) == kq) out[196608 + (size_t)m * 16 + c] = acc[c] + bso[c];
    }
}

// ----------------------------------------------------------------
extern "C" void kernel_launch(void* const* d_in, const int* in_sizes, int n_in,
                              void* d_out, int out_size, void* d_ws, size_t ws_size,
                              hipStream_t stream)
{
    (void)in_sizes; (void)n_in; (void)out_size; (void)ws_size;
    const float* s     = (const float*)d_in[0];
    const float* z     = (const float*)d_in[1];
    const float* rots  = (const float*)d_in[2];
    const float* trans = (const float*)d_in[3];
    const float* mask  = (const float*)d_in[4];
    const float* sp    = (const float*)d_in[5];
    const float* sf    = (const float*)d_in[6];
    const float* smask = (const float*)d_in[7];
    const float* Wq    = (const float*)d_in[8];  const float* bq   = (const float*)d_in[9];
    const float* Wkv   = (const float*)d_in[10]; const float* bkv  = (const float*)d_in[11];
    const float* Wqp   = (const float*)d_in[12]; const float* bqp  = (const float*)d_in[13];
    const float* Wkvp  = (const float*)d_in[14]; const float* bkvp = (const float*)d_in[15];
    const float* Wse   = (const float*)d_in[16]; const float* bse  = (const float*)d_in[17];
    const float* Wsq   = (const float*)d_in[18]; const float* bsq  = (const float*)d_in[19];
    const float* Wsk   = (const float*)d_in[20]; const float* bsk  = (const float*)d_in[21];
    const float* Wsv   = (const float*)d_in[22]; const float* bsv  = (const float*)d_in[23];
    const float* Wb    = (const float*)d_in[24]; const float* bb   = (const float*)d_in[25];
    const float* Wdz   = (const float*)d_in[26]; const float* bdz  = (const float*)d_in[27];
    const float* hw    = (const float*)d_in[28]; const float* sbw  = (const float*)d_in[29];
    const float* Wout  = (const float*)d_in[30]; const float* bout = (const float*)d_in[31];
    const float* Wso   = (const float*)d_in[32]; const float* bso  = (const float*)d_in[33];
    float* out = (float*)d_out;

    float* qw    = (float*)d_ws;
    float* kw    = qw    + (size_t)512 * 192;
    float* vw    = kw    + (size_t)512 * 192;
    float* sqw   = vw    + (size_t)512 * 192;
    float* qpw   = sqw   + (size_t)512 * 192;
    float* kpw   = qpw   + (size_t)512 * 144;
    float* vpw   = kpw   + (size_t)512 * 144;
    float* sfeat = vpw   + (size_t)512 * 288;
    float* skv   = sfeat + (size_t)2048 * 384;
    float* ocat  = skv   + (size_t)2048 * 384;
    float* sagg  = ocat  + (size_t)512 * 1152;
    // region: proj (688K) -> bpz (11.53M) -> logits (12.58M), stream-serialized
    float* region = sagg + (size_t)2048 * 384;
    float* proj   = region;
    float* bpz    = region;
    float* logits = region;
    float* wt1   = region + (size_t)2048 * 12 * 512;
    float* wt2   = wt1   + (size_t)1344 * 384;
    float* wt3   = wt2   + (size_t)384 * 384;
    float* b1    = wt3   + (size_t)384 * 1152;
    float* b2    = b1    + 1344;
    float* st    = b2    + 384;                  // s^T [384][512]
    float* wbuf  = st    + (size_t)384 * 512;    // w [2048][512]
    float* statm = wbuf  + (size_t)2048 * 512;
    float* stati = statm + (size_t)2048 * 12;

    k_pack<<<dim3(1099), dim3(256), 0, stream>>>(Wq, Wsq, Wkv, Wqp, Wkvp, Wsk, Wsv, Wout,
        bq, bsq, bkv, bqp, bkvp, bsk, bsv, wt1, wt2, wt3, b1, b2);
    k_transp<<<dim3(12, 16), dim3(256), 0, stream>>>(s, st);
    k_gemm<384, true><<<dim3(21, 8), dim3(256), 0, stream>>>(s, wt1, b1, proj, 1344);
    k_scatter<<<dim3(128), dim3(256), 0, stream>>>(proj, rots, trans,
        qw, kw, vw, sqw, qpw, kpw, vpw);
    k_sfeat<<<dim3(256), dim3(256), 0, stream>>>(sf, Wse, bse, sfeat);
    k_gemm<384, true><<<dim3(6, 32), dim3(256), 0, stream>>>(sfeat, wt2, b2, skv, 384);
    k_zpass<<<dim3(512), dim3(256), 0, stream>>>(z, Wb, bb, Wdz, bdz, bpz);
    k_attn<<<dim3(512), dim3(256), 0, stream>>>(qw, kw, vw, qpw, kpw, vpw, bpz, mask,
        rots, trans, hw, ocat);
    k_surf<<<dim3(384), dim3(256), 0, stream>>>(sqw, skv, trans, mask, sp, smask,
        sbw, ocat);
    k_tlog<<<dim3(64, 12), dim3(256), 0, stream>>>(sqw, skv, trans, mask, sp, smask,
        sbw, logits, statm, stati);
    k_tw<<<dim3(2048), dim3(256), 0, stream>>>(logits, statm, stati, wbuf);
    k_gemm<512, false><<<dim3(6, 32), dim3(256), 0, stream>>>(wbuf, st, nullptr, sagg, 384);
    k_surf_out<<<dim3(32), dim3(256), 0, stream>>>(sfeat, sagg, Wso, bso, out);
    k_gemm<1152, true><<<dim3(6, 8), dim3(256), 0, stream>>>(ocat, wt3, bout, out, 384);
}